// Round 11
// baseline (1047.990 us; speedup 1.0000x reference)
//
#include <hip/hip_runtime.h>
#include <math.h>

#define N_NODES 100000
#define N_EDGES 1600000
#define NCHUNK 8
#define CHDIV 12500                  // N_NODES / NCHUNK
#define NB_TOT (2 * N_NODES * NCHUNK) // CSR buckets: (row, chunk)
#define SCAN_NB 256
#define SCAN_CH 25                   // 256*256*25 = 1,638,400 >= NB_TOT+1

static inline int cdiv(long a, long b) { return (int)((a + b - 1) / b); }

typedef unsigned int uint;
typedef unsigned short ushort;

__device__ inline float bf2f(uint u) { return __uint_as_float(u << 16); }
__device__ inline ushort f2bf(float f) {
    uint u = __float_as_uint(f);
    uint r = ((u >> 16) & 1u) + 0x7fffu;   // RNE
    return (ushort)((u + r) >> 16);
}

// ------------- register-blocked GEMM: C[i,m] = sum_k A[i,k]*B[k,m] ----------
template <int K, int M, int R, int RT, int OUT, bool ELU, bool LOSS, bool GUARD>
__global__ __launch_bounds__(256) void gemm_rb(const float* __restrict__ A,
                                               const float* __restrict__ B,
                                               void* __restrict__ Cv,
                                               void* __restrict__ Cv2,
                                               const float* __restrict__ Xref,
                                               float* __restrict__ partial,
                                               int nrows) {
    constexpr int KC = 32;
    constexpr int TPR = M / 4;
    constexpr int G = 256 / TPR;
    static_assert(G * RT == R, "tile geometry");
    __shared__ float Blds[KC * M];
    __shared__ float Alds[KC][R];
    const int tcol = threadIdx.x % TPR;
    const int tg   = threadIdx.x / TPR;
    const int rbase = blockIdx.x * R;
    float acc[RT][4] = {};
    for (int k0 = 0; k0 < K; k0 += KC) {
        const float4* Bsrc = reinterpret_cast<const float4*>(B + (size_t)k0 * M);
        float4* Bdst = reinterpret_cast<float4*>(Blds);
#pragma unroll
        for (int i = 0; i < (KC * M / 4) / 256; ++i)
            Bdst[i * 256 + threadIdx.x] = Bsrc[i * 256 + threadIdx.x];
#pragma unroll
        for (int e = threadIdx.x; e < R * KC; e += 256) {
            int rr = e / KC, kk = e - rr * KC;
            int rg = rbase + rr;
            if (GUARD) rg = min(rg, nrows - 1);
            Alds[kk][rr] = A[(size_t)rg * K + k0 + kk];
        }
        __syncthreads();
#pragma unroll
        for (int kk = 0; kk < KC; ++kk) {
            float ar[RT];
#pragma unroll
            for (int q = 0; q < RT / 4; ++q) {
                float4 av = *reinterpret_cast<const float4*>(&Alds[kk][tg * RT + 4 * q]);
                ar[4 * q] = av.x; ar[4 * q + 1] = av.y;
                ar[4 * q + 2] = av.z; ar[4 * q + 3] = av.w;
            }
            float4 bv = *reinterpret_cast<const float4*>(&Blds[kk * M + tcol * 4]);
            float br[4] = {bv.x, bv.y, bv.z, bv.w};
#pragma unroll
            for (int i = 0; i < RT; ++i)
#pragma unroll
                for (int j = 0; j < 4; ++j)
                    acc[i][j] += ar[i] * br[j];
        }
        __syncthreads();
    }
    float lsum = 0.f;
#pragma unroll
    for (int i = 0; i < RT; ++i) {
        int r = rbase + tg * RT + i;
        if (GUARD && r >= nrows) continue;
        float o0 = acc[i][0], o1 = acc[i][1], o2 = acc[i][2], o3 = acc[i][3];
        if (ELU) {
            o0 = o0 > 0.f ? o0 : expm1f(o0);
            o1 = o1 > 0.f ? o1 : expm1f(o1);
            o2 = o2 > 0.f ? o2 : expm1f(o2);
            o3 = o3 > 0.f ? o3 : expm1f(o3);
        }
        if (OUT == 0 || OUT == 3) {
            float* c = (float*)Cv + (size_t)r * M + tcol * 4;
            c[0] = o0; c[1] = o1; c[2] = o2; c[3] = o3;
        } else if (OUT == 1) {
            float* c = (float*)Cv + (size_t)r * M + tcol * 4;
            *reinterpret_cast<float4*>(c) = make_float4(o0, o1, o2, o3);
        }
        if (OUT == 2 || OUT == 3) {
            void* dst = (OUT == 2) ? Cv : Cv2;
            ushort* c = (ushort*)dst + (size_t)r * M + tcol * 4;
            uint2 w;
            w.x = (uint)f2bf(o0) | ((uint)f2bf(o1) << 16);
            w.y = (uint)f2bf(o2) | ((uint)f2bf(o3) << 16);
            *reinterpret_cast<uint2*>(c) = w;
        }
        if (LOSS) {
            float4 xv = *reinterpret_cast<const float4*>(Xref + (size_t)r * 256 + tcol * 4);
            float d0 = o0 - xv.x, d1 = o1 - xv.y;
            float d2 = o2 - xv.z, d3 = o3 - xv.w;
            lsum += d0 * d0 + d1 * d1 + d2 * d2 + d3 * d3;
        }
    }
    if (LOSS) {
        __shared__ float smRed[4];
#pragma unroll
        for (int off = 32; off > 0; off >>= 1) lsum += __shfl_down(lsum, off);
        int lane = threadIdx.x & 63, w = threadIdx.x >> 6;
        if (lane == 0) smRed[w] = lsum;
        __syncthreads();
        if (threadIdx.x == 0)
            partial[blockIdx.x] = smRed[0] + smRed[1] + smRed[2] + smRed[3];
    }
}

// ---------------- small matrix transpose ------------------------------------
__global__ __launch_bounds__(256) void transpose_kernel(const float* __restrict__ in,
                                                        float* __restrict__ out,
                                                        int rows, int cols) {
    int i = blockIdx.x * 256 + threadIdx.x;
    if (i >= rows * cols) return;
    int r = i / cols, c = i - r * cols;
    out[c * rows + r] = in[i];
}

// ---------------- attention feature dots (bf16 H): all 4 at once ------------
__global__ __launch_bounds__(256) void attn_f4_kernel(const ushort* __restrict__ Hb,
                                                      const float* __restrict__ va,
                                                      const float* __restrict__ vb,
                                                      const float* __restrict__ pva,
                                                      const float* __restrict__ pvb,
                                                      float* __restrict__ f1,
                                                      float* __restrict__ f2,
                                                      float* __restrict__ pf1,
                                                      float* __restrict__ pf2) {
    int wid = (blockIdx.x * 256 + threadIdx.x) >> 6;
    int lane = threadIdx.x & 63;
    if (wid >= N_NODES) return;
    uint hv = reinterpret_cast<const uint*>(Hb + (size_t)wid * 128)[lane];
    float x0 = bf2f(hv & 0xffffu);
    float x1 = bf2f(hv >> 16);
    int k = 2 * lane;
    float a = x0 * va[k] + x1 * va[k + 1];
    float b = x0 * vb[k] + x1 * vb[k + 1];
    float pa = x0 * pva[k] + x1 * pva[k + 1];
    float pb = x0 * pvb[k] + x1 * pvb[k + 1];
#pragma unroll
    for (int off = 32; off > 0; off >>= 1) {
        a += __shfl_down(a, off);
        b += __shfl_down(b, off);
        pa += __shfl_down(pa, off);
        pb += __shfl_down(pb, off);
    }
    if (lane == 0) { f1[wid] = a; f2[wid] = b; pf1[wid] = pa; pf2[wid] = pb; }
}

// ---------------- chunk-sorted CSR build ------------------------------------
// bucket = row*8 + col/CHDIV; row r's full segment = [rp[8r], rp[8r+8]),
// edges chunk-sorted within each row for gather locality.
__global__ __launch_bounds__(256) void hist2_kernel(const int* __restrict__ rows,
                                                    const int* __restrict__ cols,
                                                    const int* __restrict__ prows,
                                                    const int* __restrict__ pcols,
                                                    int* __restrict__ deg) {
    int e = blockIdx.x * 256 + threadIdx.x;
    if (e >= 2 * N_EDGES) return;
    int r, c;
    if (e < N_EDGES) { r = rows[e]; c = cols[e]; }
    else { int e2 = e - N_EDGES; r = N_NODES + prows[e2]; c = pcols[e2]; }
    atomicAdd(&deg[r * NCHUNK + c / CHDIV], 1);
}

__global__ __launch_bounds__(256) void scan1_kernel(const int* __restrict__ deg,
                                                    int* __restrict__ bsum) {
    __shared__ int sm[256];
    int base = (blockIdx.x * 256 + threadIdx.x) * SCAN_CH;
    int s = 0;
#pragma unroll
    for (int i = 0; i < SCAN_CH; ++i) {
        int idx = base + i;
        if (idx < NB_TOT) s += deg[idx];
    }
    sm[threadIdx.x] = s;
    __syncthreads();
    for (int off = 128; off > 0; off >>= 1) {
        if (threadIdx.x < off) sm[threadIdx.x] += sm[threadIdx.x + off];
        __syncthreads();
    }
    if (threadIdx.x == 0) bsum[blockIdx.x] = sm[0];
}

__global__ void scan2_kernel(int* __restrict__ bsum) {
    if (threadIdx.x != 0) return;
    int run = 0;
    for (int i = 0; i < SCAN_NB; ++i) {
        int t = bsum[i];
        bsum[i] = run;
        run += t;
    }
}

__global__ __launch_bounds__(256) void scan3_kernel(const int* __restrict__ deg,
                                                    const int* __restrict__ bsum,
                                                    int* __restrict__ rp) {
    __shared__ int sm[256];
    int base = (blockIdx.x * 256 + threadIdx.x) * SCAN_CH;
    int s = 0;
#pragma unroll
    for (int i = 0; i < SCAN_CH; ++i) {
        int idx = base + i;
        if (idx < NB_TOT) s += deg[idx];
    }
    sm[threadIdx.x] = s;
    __syncthreads();
    if (threadIdx.x == 0) {
        int run = bsum[blockIdx.x];
        for (int t = 0; t < 256; ++t) { int tmp = sm[t]; sm[t] = run; run += tmp; }
    }
    __syncthreads();
    int off = sm[threadIdx.x];
#pragma unroll
    for (int i = 0; i < SCAN_CH; ++i) {
        int idx = base + i;
        if (idx < NB_TOT) { rp[idx] = off; off += deg[idx]; }
        else if (idx == NB_TOT) rp[idx] = off;
    }
}

// scatter column ids only (4B) into chunk-sorted CSR slots
__global__ __launch_bounds__(256) void scatter2_kernel(const int* __restrict__ rows,
                                                       const int* __restrict__ cols,
                                                       const int* __restrict__ prows,
                                                       const int* __restrict__ pcols,
                                                       const int* __restrict__ rp,
                                                       int* __restrict__ cur,
                                                       int* __restrict__ ccol) {
    int e = blockIdx.x * 256 + threadIdx.x;
    if (e >= 2 * N_EDGES) return;
    int r, c;
    if (e < N_EDGES) { r = rows[e]; c = cols[e]; }
    else { int e2 = e - N_EDGES; r = N_NODES + prows[e2]; c = pcols[e2]; }
    int b = r * NCHUNK + c / CHDIV;
    int pos = rp[b] + atomicAdd(&cur[b], 1);
    ccol[pos] = c;
}

// ---------------- edge values: normalized+scaled softmax weights ------------
// 16 lanes per unified row; eg[j] = {col, scale * exp(f1[r]+f2[c]) / rowsum}
__global__ __launch_bounds__(256) void edgeval_kernel(const int* __restrict__ rp,
                                                      const int* __restrict__ ccol,
                                                      const float* __restrict__ f1,
                                                      const float* __restrict__ f2,
                                                      const float* __restrict__ pf1,
                                                      const float* __restrict__ pf2,
                                                      int2* __restrict__ eg) {
    int r = blockIdx.x * 16 + (threadIdx.x >> 4);
    int sl = threadIdx.x & 15;
    bool second = r >= N_NODES;
    float f1r = second ? pf1[r - N_NODES] : f1[r];
    const float* f2t = second ? pf2 : f2;
    float scale = second ? 0.8f : 0.2f;
    int j0 = rp[r * NCHUNK], e1 = rp[r * NCHUNK + NCHUNK];
    float s = 0.f;
    for (int j = j0 + sl; j < e1; j += 16)
        s += __expf(f1r + f2t[ccol[j]]);
#pragma unroll
    for (int off = 8; off > 0; off >>= 1) s += __shfl_xor(s, off);
    float inv = s > 0.f ? scale / s : 0.f;
    for (int j = j0 + sl; j < e1; j += 16) {
        int c = ccol[j];
        float w = __expf(f1r + f2t[c]) * inv;
        eg[j] = make_int2(c, __float_as_int(w));
    }
}

// ---------------- fused SpMM on 128-wide bf16 H (encoder) -------------------
// out = elu(sum_e w1*H[c] + sum_e w2*H[c]); weights pre-normalized+scaled.
#define SPU 8
__global__ __launch_bounds__(256) void spmm_fused_kernel(const int* __restrict__ rp,
                                                         const int2* __restrict__ eg,
                                                         const ushort* __restrict__ Hb,
                                                         float* __restrict__ out) {
    int r = blockIdx.x * 4 + (threadIdx.x >> 6);
    int lane = threadIdx.x & 63;
    const uint* Hu = reinterpret_cast<const uint*>(Hb);
    float a0 = 0.f, a1 = 0.f, b0 = 0.f, b1 = 0.f;
    int j1 = rp[r * NCHUNK], E1 = rp[r * NCHUNK + NCHUNK];
    int j2 = rp[(N_NODES + r) * NCHUNK], E2 = rp[(N_NODES + r) * NCHUNK + NCHUNK];
    int c1 = max(E1 - 1, 0), c2 = max(E2 - 1, 0);
    int nb = max((E1 - j1 + SPU - 1) / SPU, (E2 - j2 + SPU - 1) / SPU);
    for (int b = 0; b < nb; ++b) {
        int2 d1[SPU], d2[SPU];
#pragma unroll
        for (int u = 0; u < SPU; ++u) d1[u] = eg[min(j1 + u, c1)];
#pragma unroll
        for (int u = 0; u < SPU; ++u) d2[u] = eg[min(j2 + u, c2)];
        uint h1[SPU], h2[SPU];
#pragma unroll
        for (int u = 0; u < SPU; ++u) h1[u] = Hu[(size_t)d1[u].x * 64 + lane];
#pragma unroll
        for (int u = 0; u < SPU; ++u) h2[u] = Hu[(size_t)d2[u].x * 64 + lane];
#pragma unroll
        for (int u = 0; u < SPU; ++u) {
            float v1 = (j1 + u < E1) ? __int_as_float(d1[u].y) : 0.f;
            float v2 = (j2 + u < E2) ? __int_as_float(d2[u].y) : 0.f;
            a0 += v1 * bf2f(h1[u] & 0xffffu);
            a1 += v1 * bf2f(h1[u] >> 16);
            b0 += v2 * bf2f(h2[u] & 0xffffu);
            b1 += v2 * bf2f(h2[u] >> 16);
        }
        j1 += SPU; j2 += SPU;
    }
    float o0 = a0 + b0;
    float o1 = a1 + b1;
    o0 = o0 > 0.f ? o0 : expm1f(o0);
    o1 = o1 > 0.f ? o1 : expm1f(o1);
    *reinterpret_cast<float2*>(out + (size_t)r * 128 + 2 * lane) = make_float2(o0, o1);
}

// ---------------- fused SpMM on 64-wide bf16 Henc (decoder, no elu) ---------
__global__ __launch_bounds__(256) void spmm64_fused_kernel(const int* __restrict__ rp,
                                                           const int2* __restrict__ eg,
                                                           const ushort* __restrict__ Hb,
                                                           float* __restrict__ S) {
    int r = blockIdx.x * 4 + (threadIdx.x >> 6);
    int lane = threadIdx.x & 63;
    float a = 0.f, b = 0.f;
    int j1 = rp[r * NCHUNK], E1 = rp[r * NCHUNK + NCHUNK];
    int j2 = rp[(N_NODES + r) * NCHUNK], E2 = rp[(N_NODES + r) * NCHUNK + NCHUNK];
    int c1 = max(E1 - 1, 0), c2 = max(E2 - 1, 0);
    int nb = max((E1 - j1 + SPU - 1) / SPU, (E2 - j2 + SPU - 1) / SPU);
    for (int bb = 0; bb < nb; ++bb) {
        int2 d1[SPU], d2[SPU];
#pragma unroll
        for (int u = 0; u < SPU; ++u) d1[u] = eg[min(j1 + u, c1)];
#pragma unroll
        for (int u = 0; u < SPU; ++u) d2[u] = eg[min(j2 + u, c2)];
        ushort h1[SPU], h2[SPU];
#pragma unroll
        for (int u = 0; u < SPU; ++u) h1[u] = Hb[(size_t)d1[u].x * 64 + lane];
#pragma unroll
        for (int u = 0; u < SPU; ++u) h2[u] = Hb[(size_t)d2[u].x * 64 + lane];
#pragma unroll
        for (int u = 0; u < SPU; ++u) {
            float v1 = (j1 + u < E1) ? __int_as_float(d1[u].y) : 0.f;
            float v2 = (j2 + u < E2) ? __int_as_float(d2[u].y) : 0.f;
            a += v1 * bf2f((uint)h1[u]);
            b += v2 * bf2f((uint)h2[u]);
        }
        j1 += SPU; j2 += SPU;
    }
    S[(size_t)r * 64 + lane] = a + b;
}

// ---------------- reductions -----------------------------------------------
__global__ __launch_bounds__(256) void sq_reduce_kernel(const float* __restrict__ a,
                                                        float* __restrict__ acc, int n) {
    __shared__ float sm[4];
    float s = 0.f;
    for (int i = blockIdx.x * 256 + threadIdx.x; i < n; i += gridDim.x * 256) {
        float d = a[i];
        s += d * d;
    }
#pragma unroll
    for (int off = 32; off > 0; off >>= 1) s += __shfl_down(s, off);
    int lane = threadIdx.x & 63, w = threadIdx.x >> 6;
    if (lane == 0) sm[w] = s;
    __syncthreads();
    if (threadIdx.x == 0) atomicAdd(acc, sm[0] + sm[1] + sm[2] + sm[3]);
}

__global__ __launch_bounds__(256) void partial_reduce_kernel(const float* __restrict__ p,
                                                             int n, float* __restrict__ acc) {
    __shared__ float sm[4];
    float s = 0.f;
    for (int i = threadIdx.x; i < n; i += 256) s += p[i];
#pragma unroll
    for (int off = 32; off > 0; off >>= 1) s += __shfl_down(s, off);
    int lane = threadIdx.x & 63, w = threadIdx.x >> 6;
    if (lane == 0) sm[w] = s;
    __syncthreads();
    if (threadIdx.x == 0) atomicAdd(acc, sm[0] + sm[1] + sm[2] + sm[3]);
}

__global__ void finalize_kernel(const float* __restrict__ acc, float* __restrict__ out) {
    out[0] = sqrtf(acc[0]) + 1e-4f * (acc[1] + acc[2]);
}

extern "C" void kernel_launch(void* const* d_in, const int* in_sizes, int n_in,
                              void* d_out, int out_size, void* d_ws, size_t ws_size,
                              hipStream_t stream) {
    const float* X    = (const float*)d_in[0];
    const float* W0   = (const float*)d_in[1];
    const float* W1   = (const float*)d_in[2];
    const float* v00  = (const float*)d_in[3];
    const float* v01  = (const float*)d_in[4];
    const float* pv00 = (const float*)d_in[5];
    const float* pv01 = (const float*)d_in[6];
    const int* rows   = (const int*)d_in[7];
    const int* cols   = (const int*)d_in[8];
    const int* prows  = (const int*)d_in[9];
    const int* pcols  = (const int*)d_in[10];

    float* out  = (float*)d_out;
    float* Henc = out + 1;                                  // N x 64 (misaligned base)
    float* Xrec = out + 1 + (size_t)N_NODES * 64;           // N x 256 (misaligned base)

    // scratch in the dead X_ region [6400001, 32000001), all overwritten at step 8:
    //   bufAh/S [ 6400004, 12800004)  N x 128 bf16, later N x 64 fp32 (bufAh dead after step 4)
    //   ccol    [12800004, 16000004)  2E int
    //   eg      [16000004, 22400004)  2E int2
    //   HencB   [22400004, 25600004)  N x 64 bf16
    //   deg/cur [25600004, 28800004)  NB_TOT x2 int
    ushort* bufAh  = (ushort*)(out + 6400004);
    float*  S      = out + 6400004;
    int*    ccol   = (int*)(out + 12800004);
    int2*   eg     = (int2*)(out + 16000004);
    ushort* HencB  = (ushort*)(out + 22400004);
    int*    deg    = (int*)(out + 25600004);
    int*    cur    = deg + NB_TOT;

    float* ws   = (float*)d_ws;
    float* bufB = ws;                                       // N x 128 fp32
    float* f1   = bufB + (size_t)N_NODES * 128;
    float* f2   = f1 + N_NODES;
    float* pf1  = f2 + N_NODES;
    float* pf2  = pf1 + N_NODES;
    float* acc  = pf2 + N_NODES;                            // 4
    float* W1T  = acc + 4;                                  // 64 x 128
    float* W0T  = W1T + 64 * 128;                           // 128 x 256
    int*   rp   = (int*)(W0T + 128 * 256);                  // NB_TOT+1
    int*   bsum = rp + NB_TOT + 1;                          // SCAN_NB
    float* partial = (float*)(bsum + SCAN_NB);              // n/32 floats

    const int n = N_NODES;
    const int EG2 = cdiv(2 * (long)N_EDGES, 256);

    // 0. weight transposes (tiny)
    transpose_kernel<<<cdiv(128 * 64, 256), 256, 0, stream>>>(W1, W1T, 128, 64);
    transpose_kernel<<<cdiv(256 * 128, 256), 256, 0, stream>>>(W0, W0T, 256, 128);

    // 1. H1 = X @ W0 -> bufAh (bf16)
    gemm_rb<256, 128, 64, 8, 2, false, false, true><<<cdiv(n, 64), 256, 0, stream>>>(
        X, W0, bufAh, nullptr, nullptr, nullptr, n);

    // zero deg+cur (2*NB_TOT ints) and acc
    hipMemsetAsync(deg, 0, 2 * (size_t)NB_TOT * sizeof(int), stream);
    hipMemsetAsync(acc, 0, 4 * sizeof(float), stream);

    // 2. attention feature dots
    attn_f4_kernel<<<cdiv(n, 4), 256, 0, stream>>>(bufAh, v00, v01, pv00, pv01,
                                                   f1, f2, pf1, pf2);

    // 3. chunk-sorted CSR build + edge weights
    hist2_kernel<<<EG2, 256, 0, stream>>>(rows, cols, prows, pcols, deg);
    scan1_kernel<<<SCAN_NB, 256, 0, stream>>>(deg, bsum);
    scan2_kernel<<<1, 64, 0, stream>>>(bsum);
    scan3_kernel<<<SCAN_NB, 256, 0, stream>>>(deg, bsum, rp);
    scatter2_kernel<<<EG2, 256, 0, stream>>>(rows, cols, prows, pcols, rp, cur, ccol);
    edgeval_kernel<<<cdiv(2 * n, 16), 256, 0, stream>>>(rp, ccol, f1, f2, pf1, pf2, eg);

    // 4. encoder: bufB = elu(spmm) (weights pre-normalized+scaled)
    spmm_fused_kernel<<<n / 4, 256, 0, stream>>>(rp, eg, bufAh, bufB);

    // 5. Henc = bufB @ W1 -> d_out (fp32) + HencB (bf16 for gather)
    gemm_rb<128, 64, 64, 4, 3, false, false, true><<<cdiv(n, 64), 256, 0, stream>>>(
        bufB, W1, Henc, HencB, nullptr, nullptr, n);

    // 6. decoder spmm on Henc (64-wide) -> S (bufAh region, now dead)
    spmm64_fused_kernel<<<n / 4, 256, 0, stream>>>(rp, eg, HencB, S);

    // 7. D = elu(S @ W1T) -> bufB
    gemm_rb<64, 128, 32, 4, 1, true, false, false><<<n / 32, 256, 0, stream>>>(
        S, W1T, bufB, nullptr, nullptr, nullptr, n);

    // 8. X_ = bufB @ W0T -> Xrec, fused loss partials
    gemm_rb<128, 256, 32, 8, 0, false, true, false><<<n / 32, 256, 0, stream>>>(
        bufB, W0T, Xrec, nullptr, X, partial, n);

    // 9. loss
    partial_reduce_kernel<<<1, 256, 0, stream>>>(partial, n / 32, acc + 0);
    sq_reduce_kernel<<<16, 256, 0, stream>>>(W0, acc + 1, 256 * 128);
    sq_reduce_kernel<<<4, 256, 0, stream>>>(W1, acc + 2, 128 * 64);
    finalize_kernel<<<1, 1, 0, stream>>>(acc, out);
}

// Round 12
// 910.829 us; speedup vs baseline: 1.1506x; 1.1506x over previous
//
#include <hip/hip_runtime.h>
#include <math.h>

#define N_NODES 100000
#define N_EDGES 1600000
#define TOT (2 * N_NODES)
#define SCAN_NB 256
#define SCAN_CH 4                    // 256*256*4 = 262144 >= 2N+1

static inline int cdiv(long a, long b) { return (int)((a + b - 1) / b); }

typedef unsigned int uint;
typedef unsigned short ushort;
typedef __attribute__((ext_vector_type(8))) short short8v;   // 8 bf16 (4 VGPR)
typedef __attribute__((ext_vector_type(4))) float f32x4;

__device__ inline float bf2f(uint u) { return __uint_as_float(u << 16); }
__device__ inline ushort f2bf(float f) {
    uint u = __float_as_uint(f);
    uint r = ((u >> 16) & 1u) + 0x7fffu;   // RNE
    return (ushort)((u + r) >> 16);
}

// ---------------- MFMA bf16 GEMM: C[i,m] = sum_k A[i,k]*B[k,m] --------------
// Bcm: B col-major bf16 [M][K+8] (padded rows, 16B-aligned). Block=256thr=4waves,
// tile BM=128 rows x M cols; wave w owns rows [w*32, w*32+32). K-step 32.
// AF32: A is fp32 (converted to bf16 at staging); else A is bf16 [nrows][K].
// OUT: 0 = fp32 scalar stores, 2 = bf16 stores. LOSS: fused sum((C-X)^2).
template <int K, int M, bool AF32, int OUT, bool LOSS>
__global__ __launch_bounds__(256) void gemm_mfma(const void* __restrict__ Av,
                                                 const ushort* __restrict__ Bcm,
                                                 void* __restrict__ Cv,
                                                 const float* __restrict__ Xref,
                                                 float* __restrict__ partial,
                                                 int nrows) {
    constexpr int BM = 128;
    constexpr int KP = K + 8;
    constexpr int NCT = M / 16;
    __shared__ ushort Blds[M * KP];
    __shared__ ushort Alds[BM * 32];
    const int w = threadIdx.x >> 6;
    const int l = threadIdx.x & 63;
    const int rowg = l & 15;          // fragment row (A) / col (B,D)
    const int kg = l >> 4;            // fragment k-group
    const int rbase = blockIdx.x * BM;
    // stage B entire [M][KP] bf16 (coalesced uint4 copy)
    {
        const uint4* src = reinterpret_cast<const uint4*>(Bcm);
        uint4* dst = reinterpret_cast<uint4*>(Blds);
        const int total = M * KP / 8;
        for (int i = threadIdx.x; i < total; i += 256) dst[i] = src[i];
    }
    f32x4 acc[2][NCT] = {};
    for (int k0 = 0; k0 < K; k0 += 32) {
        __syncthreads();
        // stage A: BM x 32 bf16
        int r = threadIdx.x >> 1;
        int kk = (threadIdx.x & 1) * 16;
        int rg = min(rbase + r, nrows - 1);
        if (AF32) {
            const float* A = (const float*)Av;
            const float4* src = reinterpret_cast<const float4*>(A + (size_t)rg * K + k0 + kk);
            ushort* dst = &Alds[r * 32 + kk];
#pragma unroll
            for (int q = 0; q < 4; ++q) {
                float4 v = src[q];
                dst[4 * q + 0] = f2bf(v.x); dst[4 * q + 1] = f2bf(v.y);
                dst[4 * q + 2] = f2bf(v.z); dst[4 * q + 3] = f2bf(v.w);
            }
        } else {
            const ushort* A = (const ushort*)Av;
            const uint4* src = reinterpret_cast<const uint4*>(A + (size_t)rg * K + k0 + kk);
            uint4* dst = reinterpret_cast<uint4*>(&Alds[r * 32 + kk]);
            dst[0] = src[0];
            dst[1] = src[1];
        }
        __syncthreads();
#pragma unroll
        for (int rt = 0; rt < 2; ++rt) {
            short8v af = *reinterpret_cast<const short8v*>(
                &Alds[(w * 32 + rt * 16 + rowg) * 32 + kg * 8]);
#pragma unroll
            for (int ct = 0; ct < NCT; ++ct) {
                short8v bf = *reinterpret_cast<const short8v*>(
                    &Blds[(ct * 16 + rowg) * KP + k0 + kg * 8]);
                acc[rt][ct] = __builtin_amdgcn_mfma_f32_16x16x32_bf16(
                    af, bf, acc[rt][ct], 0, 0, 0);
            }
        }
    }
    float lsum = 0.f;
#pragma unroll
    for (int rt = 0; rt < 2; ++rt) {
#pragma unroll
        for (int q = 0; q < 4; ++q) {
            int r = rbase + w * 32 + rt * 16 + kg * 4 + q;
            if (r >= nrows) continue;
#pragma unroll
            for (int ct = 0; ct < NCT; ++ct) {
                float o = acc[rt][ct][q];
                int col = ct * 16 + rowg;
                if (OUT == 0) ((float*)Cv)[(size_t)r * M + col] = o;
                else ((ushort*)Cv)[(size_t)r * M + col] = f2bf(o);
                if (LOSS) {
                    float d = o - Xref[(size_t)r * 256 + col];
                    lsum += d * d;
                }
            }
        }
    }
    if (LOSS) {
        __shared__ float smRed[4];
#pragma unroll
        for (int off = 32; off > 0; off >>= 1) lsum += __shfl_down(lsum, off);
        __syncthreads();
        if (l == 0) smRed[w] = lsum;
        __syncthreads();
        if (threadIdx.x == 0)
            partial[blockIdx.x] = smRed[0] + smRed[1] + smRed[2] + smRed[3];
    }
}

// ---------------- weight prep ----------------------------------------------
__global__ __launch_bounds__(256) void transpose_kernel(const float* __restrict__ in,
                                                        float* __restrict__ out,
                                                        int rows, int cols) {
    int i = blockIdx.x * 256 + threadIdx.x;
    if (i >= rows * cols) return;
    int r = i / cols, c = i - r * cols;
    out[c * rows + r] = in[i];
}

// B1cm[m][k] = bf16(W0[k][m]) for gemm1 (B = W0, K=256, M=128), pad 264
__global__ __launch_bounds__(256) void prepB1_kernel(const float* __restrict__ W0,
                                                     ushort* __restrict__ B1cm) {
    int i = blockIdx.x * 256 + threadIdx.x;
    if (i >= 256 * 128) return;
    int k = i / 128, m = i - k * 128;
    B1cm[m * 264 + k] = f2bf(W0[(size_t)k * 128 + m]);
}

// B8cm[m][k] = bf16(W0T[k][m]) = bf16(W0[m][k]) for gemm8 (B = W0T, K=128, M=256), pad 136
__global__ __launch_bounds__(256) void prepB8_kernel(const float* __restrict__ W0,
                                                     ushort* __restrict__ B8cm) {
    int i = blockIdx.x * 256 + threadIdx.x;
    if (i >= 256 * 128) return;
    int m = i / 128, k = i - m * 128;
    B8cm[m * 136 + k] = f2bf(W0[(size_t)m * 128 + k]);
}

// ------------- register-blocked VALU GEMM (small GEMMs) ---------------------
// OUT: 0 = fp32 scalar, 1 = fp32 float4, 2 = bf16, 3 = fp32 + bf16 copy
template <int K, int M, int R, int RT, int OUT, bool ELU, bool LOSS, bool GUARD>
__global__ __launch_bounds__(256) void gemm_rb(const float* __restrict__ A,
                                               const float* __restrict__ B,
                                               void* __restrict__ Cv,
                                               void* __restrict__ Cv2,
                                               const float* __restrict__ Xref,
                                               float* __restrict__ partial,
                                               int nrows) {
    constexpr int KC = 32;
    constexpr int TPR = M / 4;
    constexpr int G = 256 / TPR;
    static_assert(G * RT == R, "tile geometry");
    __shared__ float Blds[KC * M];
    __shared__ float Alds[KC][R];
    const int tcol = threadIdx.x % TPR;
    const int tg   = threadIdx.x / TPR;
    const int rbase = blockIdx.x * R;
    float acc[RT][4] = {};
    for (int k0 = 0; k0 < K; k0 += KC) {
        const float4* Bsrc = reinterpret_cast<const float4*>(B + (size_t)k0 * M);
        float4* Bdst = reinterpret_cast<float4*>(Blds);
#pragma unroll
        for (int i = 0; i < (KC * M / 4) / 256; ++i)
            Bdst[i * 256 + threadIdx.x] = Bsrc[i * 256 + threadIdx.x];
#pragma unroll
        for (int e = threadIdx.x; e < R * KC; e += 256) {
            int rr = e / KC, kk = e - rr * KC;
            int rg = rbase + rr;
            if (GUARD) rg = min(rg, nrows - 1);
            Alds[kk][rr] = A[(size_t)rg * K + k0 + kk];
        }
        __syncthreads();
#pragma unroll
        for (int kk = 0; kk < KC; ++kk) {
            float ar[RT];
#pragma unroll
            for (int q = 0; q < RT / 4; ++q) {
                float4 av = *reinterpret_cast<const float4*>(&Alds[kk][tg * RT + 4 * q]);
                ar[4 * q] = av.x; ar[4 * q + 1] = av.y;
                ar[4 * q + 2] = av.z; ar[4 * q + 3] = av.w;
            }
            float4 bv = *reinterpret_cast<const float4*>(&Blds[kk * M + tcol * 4]);
            float br[4] = {bv.x, bv.y, bv.z, bv.w};
#pragma unroll
            for (int i = 0; i < RT; ++i)
#pragma unroll
                for (int j = 0; j < 4; ++j)
                    acc[i][j] += ar[i] * br[j];
        }
        __syncthreads();
    }
#pragma unroll
    for (int i = 0; i < RT; ++i) {
        int r = rbase + tg * RT + i;
        if (GUARD && r >= nrows) continue;
        float o0 = acc[i][0], o1 = acc[i][1], o2 = acc[i][2], o3 = acc[i][3];
        if (ELU) {
            o0 = o0 > 0.f ? o0 : expm1f(o0);
            o1 = o1 > 0.f ? o1 : expm1f(o1);
            o2 = o2 > 0.f ? o2 : expm1f(o2);
            o3 = o3 > 0.f ? o3 : expm1f(o3);
        }
        if (OUT == 0 || OUT == 3) {
            float* c = (float*)Cv + (size_t)r * M + tcol * 4;
            c[0] = o0; c[1] = o1; c[2] = o2; c[3] = o3;
        } else if (OUT == 1) {
            float* c = (float*)Cv + (size_t)r * M + tcol * 4;
            *reinterpret_cast<float4*>(c) = make_float4(o0, o1, o2, o3);
        }
        if (OUT == 2 || OUT == 3) {
            void* dst = (OUT == 2) ? Cv : Cv2;
            ushort* c = (ushort*)dst + (size_t)r * M + tcol * 4;
            uint2 wv;
            wv.x = (uint)f2bf(o0) | ((uint)f2bf(o1) << 16);
            wv.y = (uint)f2bf(o2) | ((uint)f2bf(o3) << 16);
            *reinterpret_cast<uint2*>(c) = wv;
        }
    }
}

// ---------------- attention feature dots (bf16 H): all 4 at once ------------
__global__ __launch_bounds__(256) void attn_f4_kernel(const ushort* __restrict__ Hb,
                                                      const float* __restrict__ va,
                                                      const float* __restrict__ vb,
                                                      const float* __restrict__ pva,
                                                      const float* __restrict__ pvb,
                                                      float* __restrict__ f1,
                                                      float* __restrict__ f2,
                                                      float* __restrict__ pf1,
                                                      float* __restrict__ pf2) {
    int wid = (blockIdx.x * 256 + threadIdx.x) >> 6;
    int lane = threadIdx.x & 63;
    if (wid >= N_NODES) return;
    uint hv = reinterpret_cast<const uint*>(Hb + (size_t)wid * 128)[lane];
    float x0 = bf2f(hv & 0xffffu);
    float x1 = bf2f(hv >> 16);
    int k = 2 * lane;
    float a = x0 * va[k] + x1 * va[k + 1];
    float b = x0 * vb[k] + x1 * vb[k + 1];
    float pa = x0 * pva[k] + x1 * pva[k + 1];
    float pb = x0 * pvb[k] + x1 * pvb[k + 1];
#pragma unroll
    for (int off = 32; off > 0; off >>= 1) {
        a += __shfl_down(a, off);
        b += __shfl_down(b, off);
        pa += __shfl_down(pa, off);
        pb += __shfl_down(pb, off);
    }
    if (lane == 0) { f1[wid] = a; f2[wid] = b; pf1[wid] = pa; pf2[wid] = pb; }
}

// ---------------- unified CSR build (2N rows) -------------------------------
__global__ __launch_bounds__(256) void hist2_kernel(const int* __restrict__ rows,
                                                    const int* __restrict__ prows,
                                                    int* __restrict__ deg) {
    int e = blockIdx.x * 256 + threadIdx.x;
    if (e >= 2 * N_EDGES) return;
    int r = e < N_EDGES ? rows[e] : N_NODES + prows[e - N_EDGES];
    atomicAdd(&deg[r], 1);
}

__global__ __launch_bounds__(256) void scan1_kernel(const int* __restrict__ deg,
                                                    int* __restrict__ bsum) {
    __shared__ int sm[256];
    int base = (blockIdx.x * 256 + threadIdx.x) * SCAN_CH;
    int s = 0;
#pragma unroll
    for (int i = 0; i < SCAN_CH; ++i) {
        int idx = base + i;
        if (idx < TOT) s += deg[idx];
    }
    sm[threadIdx.x] = s;
    __syncthreads();
    for (int off = 128; off > 0; off >>= 1) {
        if (threadIdx.x < off) sm[threadIdx.x] += sm[threadIdx.x + off];
        __syncthreads();
    }
    if (threadIdx.x == 0) bsum[blockIdx.x] = sm[0];
}

__global__ void scan2_kernel(int* __restrict__ bsum) {
    if (threadIdx.x != 0) return;
    int run = 0;
    for (int i = 0; i < SCAN_NB; ++i) {
        int t = bsum[i];
        bsum[i] = run;
        run += t;
    }
}

__global__ __launch_bounds__(256) void scan3_kernel(const int* __restrict__ deg,
                                                    const int* __restrict__ bsum,
                                                    int* __restrict__ rp) {
    __shared__ int sm[256];
    int base = (blockIdx.x * 256 + threadIdx.x) * SCAN_CH;
    int s = 0;
#pragma unroll
    for (int i = 0; i < SCAN_CH; ++i) {
        int idx = base + i;
        if (idx < TOT) s += deg[idx];
    }
    sm[threadIdx.x] = s;
    __syncthreads();
    if (threadIdx.x == 0) {
        int run = bsum[blockIdx.x];
        for (int t = 0; t < 256; ++t) { int tmp = sm[t]; sm[t] = run; run += tmp; }
    }
    __syncthreads();
    int off = sm[threadIdx.x];
#pragma unroll
    for (int i = 0; i < SCAN_CH; ++i) {
        int idx = base + i;
        if (idx < TOT) { rp[idx] = off; off += deg[idx]; }
        else if (idx == TOT) rp[idx] = off;
    }
}

__global__ __launch_bounds__(256) void scatter2_kernel(const int* __restrict__ rows,
                                                       const int* __restrict__ cols,
                                                       const int* __restrict__ prows,
                                                       const int* __restrict__ pcols,
                                                       const int* __restrict__ rp,
                                                       int* __restrict__ cur,
                                                       int* __restrict__ ccol) {
    int e = blockIdx.x * 256 + threadIdx.x;
    if (e >= 2 * N_EDGES) return;
    int r, c;
    if (e < N_EDGES) { r = rows[e]; c = cols[e]; }
    else { int e2 = e - N_EDGES; r = N_NODES + prows[e2]; c = pcols[e2]; }
    int pos = rp[r] + atomicAdd(&cur[r], 1);
    ccol[pos] = c;
}

// ---------------- edge values: normalized+scaled softmax weights ------------
__global__ __launch_bounds__(256) void edgeval_kernel(const int* __restrict__ rp,
                                                      const int* __restrict__ ccol,
                                                      const float* __restrict__ f1,
                                                      const float* __restrict__ f2,
                                                      const float* __restrict__ pf1,
                                                      const float* __restrict__ pf2,
                                                      int2* __restrict__ eg) {
    int r = blockIdx.x * 16 + (threadIdx.x >> 4);
    int sl = threadIdx.x & 15;
    bool second = r >= N_NODES;
    float f1r = second ? pf1[r - N_NODES] : f1[r];
    const float* f2t = second ? pf2 : f2;
    float scale = second ? 0.8f : 0.2f;
    int j0 = rp[r], e1 = rp[r + 1];
    float s = 0.f;
    for (int j = j0 + sl; j < e1; j += 16)
        s += __expf(f1r + f2t[ccol[j]]);
#pragma unroll
    for (int off = 8; off > 0; off >>= 1) s += __shfl_xor(s, off);
    float inv = s > 0.f ? scale / s : 0.f;
    for (int j = j0 + sl; j < e1; j += 16) {
        int c = ccol[j];
        float wv = __expf(f1r + f2t[c]) * inv;
        eg[j] = make_int2(c, __float_as_int(wv));
    }
}

// ---------------- fused SpMM on 128-wide bf16 H (encoder) -------------------
#define SPU 8
__global__ __launch_bounds__(256) void spmm_fused_kernel(const int* __restrict__ rp,
                                                         const int2* __restrict__ eg,
                                                         const ushort* __restrict__ Hb,
                                                         float* __restrict__ out) {
    int r = blockIdx.x * 4 + (threadIdx.x >> 6);
    int lane = threadIdx.x & 63;
    const uint* Hu = reinterpret_cast<const uint*>(Hb);
    float a0 = 0.f, a1 = 0.f, b0 = 0.f, b1 = 0.f;
    int j1 = rp[r], E1 = rp[r + 1];
    int j2 = rp[N_NODES + r], E2 = rp[N_NODES + r + 1];
    int c1 = max(E1 - 1, 0), c2 = max(E2 - 1, 0);
    int nb = max((E1 - j1 + SPU - 1) / SPU, (E2 - j2 + SPU - 1) / SPU);
    for (int b = 0; b < nb; ++b) {
        int2 d1[SPU], d2[SPU];
#pragma unroll
        for (int u = 0; u < SPU; ++u) d1[u] = eg[min(j1 + u, c1)];
#pragma unroll
        for (int u = 0; u < SPU; ++u) d2[u] = eg[min(j2 + u, c2)];
        uint h1[SPU], h2[SPU];
#pragma unroll
        for (int u = 0; u < SPU; ++u) h1[u] = Hu[(size_t)d1[u].x * 64 + lane];
#pragma unroll
        for (int u = 0; u < SPU; ++u) h2[u] = Hu[(size_t)d2[u].x * 64 + lane];
#pragma unroll
        for (int u = 0; u < SPU; ++u) {
            float v1 = (j1 + u < E1) ? __int_as_float(d1[u].y) : 0.f;
            float v2 = (j2 + u < E2) ? __int_as_float(d2[u].y) : 0.f;
            a0 += v1 * bf2f(h1[u] & 0xffffu);
            a1 += v1 * bf2f(h1[u] >> 16);
            b0 += v2 * bf2f(h2[u] & 0xffffu);
            b1 += v2 * bf2f(h2[u] >> 16);
        }
        j1 += SPU; j2 += SPU;
    }
    float o0 = a0 + b0;
    float o1 = a1 + b1;
    o0 = o0 > 0.f ? o0 : expm1f(o0);
    o1 = o1 > 0.f ? o1 : expm1f(o1);
    *reinterpret_cast<float2*>(out + (size_t)r * 128 + 2 * lane) = make_float2(o0, o1);
}

// ---------------- fused SpMM on 64-wide bf16 Henc (decoder) -----------------
__global__ __launch_bounds__(256) void spmm64_fused_kernel(const int* __restrict__ rp,
                                                           const int2* __restrict__ eg,
                                                           const ushort* __restrict__ Hb,
                                                           float* __restrict__ S) {
    int r = blockIdx.x * 4 + (threadIdx.x >> 6);
    int lane = threadIdx.x & 63;
    float a = 0.f, b = 0.f;
    int j1 = rp[r], E1 = rp[r + 1];
    int j2 = rp[N_NODES + r], E2 = rp[N_NODES + r + 1];
    int c1 = max(E1 - 1, 0), c2 = max(E2 - 1, 0);
    int nb = max((E1 - j1 + SPU - 1) / SPU, (E2 - j2 + SPU - 1) / SPU);
    for (int bb = 0; bb < nb; ++bb) {
        int2 d1[SPU], d2[SPU];
#pragma unroll
        for (int u = 0; u < SPU; ++u) d1[u] = eg[min(j1 + u, c1)];
#pragma unroll
        for (int u = 0; u < SPU; ++u) d2[u] = eg[min(j2 + u, c2)];
        ushort h1[SPU], h2[SPU];
#pragma unroll
        for (int u = 0; u < SPU; ++u) h1[u] = Hb[(size_t)d1[u].x * 64 + lane];
#pragma unroll
        for (int u = 0; u < SPU; ++u) h2[u] = Hb[(size_t)d2[u].x * 64 + lane];
#pragma unroll
        for (int u = 0; u < SPU; ++u) {
            float v1 = (j1 + u < E1) ? __int_as_float(d1[u].y) : 0.f;
            float v2 = (j2 + u < E2) ? __int_as_float(d2[u].y) : 0.f;
            a += v1 * bf2f((uint)h1[u]);
            b += v2 * bf2f((uint)h2[u]);
        }
        j1 += SPU; j2 += SPU;
    }
    S[(size_t)r * 64 + lane] = a + b;
}

// ---------------- reductions -----------------------------------------------
__global__ __launch_bounds__(256) void sq_reduce_kernel(const float* __restrict__ a,
                                                        float* __restrict__ acc, int n) {
    __shared__ float sm[4];
    float s = 0.f;
    for (int i = blockIdx.x * 256 + threadIdx.x; i < n; i += gridDim.x * 256) {
        float d = a[i];
        s += d * d;
    }
#pragma unroll
    for (int off = 32; off > 0; off >>= 1) s += __shfl_down(s, off);
    int lane = threadIdx.x & 63, w = threadIdx.x >> 6;
    if (lane == 0) sm[w] = s;
    __syncthreads();
    if (threadIdx.x == 0) atomicAdd(acc, sm[0] + sm[1] + sm[2] + sm[3]);
}

__global__ __launch_bounds__(256) void partial_reduce_kernel(const float* __restrict__ p,
                                                             int n, float* __restrict__ acc) {
    __shared__ float sm[4];
    float s = 0.f;
    for (int i = threadIdx.x; i < n; i += 256) s += p[i];
#pragma unroll
    for (int off = 32; off > 0; off >>= 1) s += __shfl_down(s, off);
    int lane = threadIdx.x & 63, w = threadIdx.x >> 6;
    if (lane == 0) sm[w] = s;
    __syncthreads();
    if (threadIdx.x == 0) atomicAdd(acc, sm[0] + sm[1] + sm[2] + sm[3]);
}

__global__ void finalize_kernel(const float* __restrict__ acc, float* __restrict__ out) {
    out[0] = sqrtf(acc[0]) + 1e-4f * (acc[1] + acc[2]);
}

extern "C" void kernel_launch(void* const* d_in, const int* in_sizes, int n_in,
                              void* d_out, int out_size, void* d_ws, size_t ws_size,
                              hipStream_t stream) {
    const float* X    = (const float*)d_in[0];
    const float* W0   = (const float*)d_in[1];
    const float* W1   = (const float*)d_in[2];
    const float* v00  = (const float*)d_in[3];
    const float* v01  = (const float*)d_in[4];
    const float* pv00 = (const float*)d_in[5];
    const float* pv01 = (const float*)d_in[6];
    const int* rows   = (const int*)d_in[7];
    const int* cols   = (const int*)d_in[8];
    const int* prows  = (const int*)d_in[9];
    const int* pcols  = (const int*)d_in[10];

    float* out  = (float*)d_out;
    float* Henc = out + 1;                                  // N x 64 (misaligned base)
    float* Xrec = out + 1 + (size_t)N_NODES * 64;           // N x 256 (misaligned base)

    // scratch in the dead X_ region [6400001, 32000001):
    //   bufAh/S [ 6400004, 12800004)  N x 128 bf16; later N x 64 fp32 (S)
    //   ccol    [12800004, 16000004)  2E int
    //   eg      [16000004, 22400004)  2E int2
    //   HencB   [22400004, 25600004)  N x 64 bf16
    //   deg/cur [25600004, 26000004)  2N + 2N int
    ushort* bufAh  = (ushort*)(out + 6400004);
    float*  S      = out + 6400004;
    int*    ccol   = (int*)(out + 12800004);
    int2*   eg     = (int2*)(out + 16000004);
    ushort* HencB  = (ushort*)(out + 22400004);
    int*    deg    = (int*)(out + 25600004);
    int*    cur    = deg + TOT;

    float* ws   = (float*)d_ws;
    float* bufB = ws;                                       // N x 128 fp32 (enc) / bf16 (dec)
    ushort* bufBh = (ushort*)bufB;
    float* f1   = bufB + (size_t)N_NODES * 128;
    float* f2   = f1 + N_NODES;
    float* pf1  = f2 + N_NODES;
    float* pf2  = pf1 + N_NODES;
    float* acc  = pf2 + N_NODES;                            // 4
    float* W1T  = acc + 4;                                  // 64 x 128 fp32
    float* W0T  = W1T + 64 * 128;                           // 128 x 256 fp32
    ushort* B1cm = (ushort*)(W0T + 128 * 256);              // 128 x 264 bf16
    ushort* B8cm = B1cm + 128 * 264;                        // 256 x 136 bf16
    int*   rp   = (int*)(B8cm + 256 * 136);                 // 2N+1
    int*   bsum = rp + TOT + 1;                             // SCAN_NB
    float* partial = (float*)(bsum + SCAN_NB);              // cdiv(n,128) floats

    const int n = N_NODES;
    const int EG2 = cdiv(2 * (long)N_EDGES, 256);

    // 0. weight prep
    transpose_kernel<<<cdiv(128 * 64, 256), 256, 0, stream>>>(W1, W1T, 128, 64);
    transpose_kernel<<<cdiv(256 * 128, 256), 256, 0, stream>>>(W0, W0T, 256, 128);
    prepB1_kernel<<<cdiv(256 * 128, 256), 256, 0, stream>>>(W0, B1cm);
    prepB8_kernel<<<cdiv(256 * 128, 256), 256, 0, stream>>>(W0, B8cm);

    // 1. H1 = X @ W0 -> bufAh (bf16), MFMA
    gemm_mfma<256, 128, true, 2, false><<<cdiv(n, 128), 256, 0, stream>>>(
        X, B1cm, bufAh, nullptr, nullptr, n);

    // zero deg+cur (2*2N ints) and acc
    hipMemsetAsync(deg, 0, 2 * (size_t)TOT * sizeof(int), stream);
    hipMemsetAsync(acc, 0, 4 * sizeof(float), stream);

    // 2. attention feature dots
    attn_f4_kernel<<<cdiv(n, 4), 256, 0, stream>>>(bufAh, v00, v01, pv00, pv01,
                                                   f1, f2, pf1, pf2);

    // 3. CSR build + pre-scaled softmax edge weights
    hist2_kernel<<<EG2, 256, 0, stream>>>(rows, prows, deg);
    scan1_kernel<<<SCAN_NB, 256, 0, stream>>>(deg, bsum);
    scan2_kernel<<<1, 64, 0, stream>>>(bsum);
    scan3_kernel<<<SCAN_NB, 256, 0, stream>>>(deg, bsum, rp);
    scatter2_kernel<<<EG2, 256, 0, stream>>>(rows, cols, prows, pcols, rp, cur, ccol);
    edgeval_kernel<<<cdiv(2 * n, 16), 256, 0, stream>>>(rp, ccol, f1, f2, pf1, pf2, eg);

    // 4. encoder: bufB(fp32) = elu(spmm)
    spmm_fused_kernel<<<n / 4, 256, 0, stream>>>(rp, eg, bufAh, bufB);

    // 5. Henc = bufB @ W1 -> d_out (fp32) + HencB (bf16 for gather)
    gemm_rb<128, 64, 64, 4, 3, false, false, true><<<cdiv(n, 64), 256, 0, stream>>>(
        bufB, W1, Henc, HencB, nullptr, nullptr, n);

    // 6. decoder spmm on Henc (64-wide) -> S (bufAh region, now dead)
    spmm64_fused_kernel<<<n / 4, 256, 0, stream>>>(rp, eg, HencB, S);

    // 7. D = elu(S @ W1T) -> bufBh (bf16, feeds MFMA gemm8)
    gemm_rb<64, 128, 32, 4, 2, true, false, false><<<n / 32, 256, 0, stream>>>(
        S, W1T, bufBh, nullptr, nullptr, nullptr, n);

    // 8. X_ = bufBh @ W0T -> Xrec + fused loss partials, MFMA
    gemm_mfma<128, 256, false, 0, true><<<cdiv(n, 128), 256, 0, stream>>>(
        bufBh, B8cm, Xrec, X, partial, n);

    // 9. loss
    partial_reduce_kernel<<<1, 256, 0, stream>>>(partial, cdiv(n, 128), acc + 0);
    sq_reduce_kernel<<<16, 256, 0, stream>>>(W0, acc + 1, 256 * 128);
    sq_reduce_kernel<<<4, 256, 0, stream>>>(W1, acc + 2, 128 * 64);
    finalize_kernel<<<1, 1, 0, stream>>>(acc, out);
}

// Round 13
// 823.202 us; speedup vs baseline: 1.2731x; 1.1064x over previous
//
#include <hip/hip_runtime.h>
#include <math.h>

#define N_NODES 100000
#define N_EDGES 1600000
#define TOT (2 * N_NODES)
#define SCAN_NB 256
#define SCAN_CH 4                    // 256*256*4 = 262144 >= 2N+1
#define RPB 25000                    // rows per scatter bucket (N/4)

static inline int cdiv(long a, long b) { return (int)((a + b - 1) / b); }

typedef unsigned int uint;
typedef unsigned short ushort;
typedef __attribute__((ext_vector_type(8))) short short8v;   // 8 bf16 (4 VGPR)
typedef __attribute__((ext_vector_type(4))) float f32x4;

__device__ inline float bf2f(uint u) { return __uint_as_float(u << 16); }
__device__ inline ushort f2bf(float f) {
    uint u = __float_as_uint(f);
    uint r = ((u >> 16) & 1u) + 0x7fffu;   // RNE
    return (ushort)((u + r) >> 16);
}

// ---------------- MFMA bf16 GEMM: C[i,m] = sum_k A[i,k]*B[k,m] --------------
// Bcm: B col-major bf16 [M][K+8]. Block=256thr=4waves; tile BM=128 x M; K-step 32.
// AF32: A fp32 (bf16-converted at staging) else bf16. OUT: 0=fp32, 2=bf16,
// 3=fp32->Cv + bf16->Cv2. ELU applied pre-store. LOSS: fused sum((C-X)^2).
template <int K, int M, bool AF32, int OUT, bool ELU, bool LOSS>
__global__ __launch_bounds__(256) void gemm_mfma(const void* __restrict__ Av,
                                                 const ushort* __restrict__ Bcm,
                                                 void* __restrict__ Cv,
                                                 void* __restrict__ Cv2,
                                                 const float* __restrict__ Xref,
                                                 float* __restrict__ partial,
                                                 int nrows) {
    constexpr int BM = 128;
    constexpr int KP = K + 8;
    constexpr int NCT = M / 16;
    __shared__ ushort Blds[M * KP];
    __shared__ ushort Alds[BM * 32];
    const int w = threadIdx.x >> 6;
    const int l = threadIdx.x & 63;
    const int rowg = l & 15;
    const int kg = l >> 4;
    const int rbase = blockIdx.x * BM;
    {
        const uint4* src = reinterpret_cast<const uint4*>(Bcm);
        uint4* dst = reinterpret_cast<uint4*>(Blds);
        const int total = M * KP / 8;
        for (int i = threadIdx.x; i < total; i += 256) dst[i] = src[i];
    }
    f32x4 acc[2][NCT] = {};
    for (int k0 = 0; k0 < K; k0 += 32) {
        __syncthreads();
        int r = threadIdx.x >> 1;
        int kk = (threadIdx.x & 1) * 16;
        int rg = min(rbase + r, nrows - 1);
        if (AF32) {
            const float* A = (const float*)Av;
            const float4* src = reinterpret_cast<const float4*>(A + (size_t)rg * K + k0 + kk);
            ushort* dst = &Alds[r * 32 + kk];
#pragma unroll
            for (int q = 0; q < 4; ++q) {
                float4 v = src[q];
                dst[4 * q + 0] = f2bf(v.x); dst[4 * q + 1] = f2bf(v.y);
                dst[4 * q + 2] = f2bf(v.z); dst[4 * q + 3] = f2bf(v.w);
            }
        } else {
            const ushort* A = (const ushort*)Av;
            const uint4* src = reinterpret_cast<const uint4*>(A + (size_t)rg * K + k0 + kk);
            uint4* dst = reinterpret_cast<uint4*>(&Alds[r * 32 + kk]);
            dst[0] = src[0];
            dst[1] = src[1];
        }
        __syncthreads();
#pragma unroll
        for (int rt = 0; rt < 2; ++rt) {
            short8v af = *reinterpret_cast<const short8v*>(
                &Alds[(w * 32 + rt * 16 + rowg) * 32 + kg * 8]);
#pragma unroll
            for (int ct = 0; ct < NCT; ++ct) {
                short8v bf = *reinterpret_cast<const short8v*>(
                    &Blds[(ct * 16 + rowg) * KP + k0 + kg * 8]);
                acc[rt][ct] = __builtin_amdgcn_mfma_f32_16x16x32_bf16(
                    af, bf, acc[rt][ct], 0, 0, 0);
            }
        }
    }
    float lsum = 0.f;
#pragma unroll
    for (int rt = 0; rt < 2; ++rt) {
#pragma unroll
        for (int q = 0; q < 4; ++q) {
            int r = rbase + w * 32 + rt * 16 + kg * 4 + q;
            if (r >= nrows) continue;
#pragma unroll
            for (int ct = 0; ct < NCT; ++ct) {
                float o = acc[rt][ct][q];
                if (ELU) o = o > 0.f ? o : expm1f(o);
                int col = ct * 16 + rowg;
                if (OUT == 0 || OUT == 3) ((float*)Cv)[(size_t)r * M + col] = o;
                if (OUT == 2) ((ushort*)Cv)[(size_t)r * M + col] = f2bf(o);
                if (OUT == 3) ((ushort*)Cv2)[(size_t)r * M + col] = f2bf(o);
                if (LOSS) {
                    float d = o - Xref[(size_t)r * 256 + col];
                    lsum += d * d;
                }
            }
        }
    }
    if (LOSS) {
        __shared__ float smRed[4];
#pragma unroll
        for (int off = 32; off > 0; off >>= 1) lsum += __shfl_down(lsum, off);
        __syncthreads();
        if (l == 0) smRed[w] = lsum;
        __syncthreads();
        if (threadIdx.x == 0)
            partial[blockIdx.x] = smRed[0] + smRed[1] + smRed[2] + smRed[3];
    }
}

// ---------------- weight prep (bf16 col-major padded) -----------------------
__global__ __launch_bounds__(256) void prepB1_kernel(const float* __restrict__ W0,
                                                     ushort* __restrict__ B) {
    int i = blockIdx.x * 256 + threadIdx.x;
    if (i >= 256 * 128) return;
    int k = i / 128, m = i - k * 128;
    B[m * 264 + k] = f2bf(W0[i]);           // B1[k][m] = W0[k][m], K=256,M=128
}
__global__ __launch_bounds__(256) void prepB5_kernel(const float* __restrict__ W1,
                                                     ushort* __restrict__ B) {
    int i = blockIdx.x * 256 + threadIdx.x;
    if (i >= 128 * 64) return;
    int k = i / 64, m = i - k * 64;
    B[m * 136 + k] = f2bf(W1[i]);           // B5[k][m] = W1[k][m], K=128,M=64
}
__global__ __launch_bounds__(256) void prepB7_kernel(const float* __restrict__ W1,
                                                     ushort* __restrict__ B) {
    int i = blockIdx.x * 256 + threadIdx.x;
    if (i >= 128 * 64) return;
    int m = i / 64, k = i - m * 64;
    B[m * 72 + k] = f2bf(W1[i]);            // B7[k][m] = W1T[k][m] = W1[m][k], K=64,M=128
}
__global__ __launch_bounds__(256) void prepB8_kernel(const float* __restrict__ W0,
                                                     ushort* __restrict__ B) {
    int i = blockIdx.x * 256 + threadIdx.x;
    if (i >= 256 * 128) return;
    int m = i / 128, k = i - m * 128;
    B[m * 136 + k] = f2bf(W0[i]);           // B8[k][m] = W0T[k][m] = W0[m][k], K=128,M=256
}

// ---------------- attention feature dots (bf16 H): all 4 at once ------------
__global__ __launch_bounds__(256) void attn_f4_kernel(const ushort* __restrict__ Hb,
                                                      const float* __restrict__ va,
                                                      const float* __restrict__ vb,
                                                      const float* __restrict__ pva,
                                                      const float* __restrict__ pvb,
                                                      float* __restrict__ f1,
                                                      float* __restrict__ f2,
                                                      float* __restrict__ pf1,
                                                      float* __restrict__ pf2) {
    int wid = (blockIdx.x * 256 + threadIdx.x) >> 6;
    int lane = threadIdx.x & 63;
    if (wid >= N_NODES) return;
    uint hv = reinterpret_cast<const uint*>(Hb + (size_t)wid * 128)[lane];
    float x0 = bf2f(hv & 0xffffu);
    float x1 = bf2f(hv >> 16);
    int k = 2 * lane;
    float a = x0 * va[k] + x1 * va[k + 1];
    float b = x0 * vb[k] + x1 * vb[k + 1];
    float pa = x0 * pva[k] + x1 * pva[k + 1];
    float pb = x0 * pvb[k] + x1 * pvb[k + 1];
#pragma unroll
    for (int off = 32; off > 0; off >>= 1) {
        a += __shfl_down(a, off);
        b += __shfl_down(b, off);
        pa += __shfl_down(pa, off);
        pb += __shfl_down(pb, off);
    }
    if (lane == 0) { f1[wid] = a; f2[wid] = b; pf1[wid] = pa; pf2[wid] = pb; }
}

// ---------------- CSR build (2N rows, rows padded to multiple of 8) ---------
__global__ __launch_bounds__(256) void hist2_kernel(const int* __restrict__ rows,
                                                    const int* __restrict__ prows,
                                                    int* __restrict__ deg) {
    int e = blockIdx.x * 256 + threadIdx.x;
    if (e >= 2 * N_EDGES) return;
    int r = e < N_EDGES ? rows[e] : N_NODES + prows[e - N_EDGES];
    atomicAdd(&deg[r], 1);
}

__device__ inline int pad8(int d) { return (d + 7) & ~7; }

__global__ __launch_bounds__(256) void scan1_kernel(const int* __restrict__ deg,
                                                    int* __restrict__ bsum) {
    __shared__ int sm[256];
    int base = (blockIdx.x * 256 + threadIdx.x) * SCAN_CH;
    int s = 0;
#pragma unroll
    for (int i = 0; i < SCAN_CH; ++i) {
        int idx = base + i;
        if (idx < TOT) s += pad8(deg[idx]);
    }
    sm[threadIdx.x] = s;
    __syncthreads();
    for (int off = 128; off > 0; off >>= 1) {
        if (threadIdx.x < off) sm[threadIdx.x] += sm[threadIdx.x + off];
        __syncthreads();
    }
    if (threadIdx.x == 0) bsum[blockIdx.x] = sm[0];
}

__global__ void scan2_kernel(int* __restrict__ bsum) {
    if (threadIdx.x != 0) return;
    int run = 0;
    for (int i = 0; i < SCAN_NB; ++i) {
        int t = bsum[i];
        bsum[i] = run;
        run += t;
    }
}

__global__ __launch_bounds__(256) void scan3_kernel(const int* __restrict__ deg,
                                                    const int* __restrict__ bsum,
                                                    int* __restrict__ rp) {
    __shared__ int sm[256];
    int base = (blockIdx.x * 256 + threadIdx.x) * SCAN_CH;
    int s = 0;
#pragma unroll
    for (int i = 0; i < SCAN_CH; ++i) {
        int idx = base + i;
        if (idx < TOT) s += pad8(deg[idx]);
    }
    sm[threadIdx.x] = s;
    __syncthreads();
    if (threadIdx.x == 0) {
        int run = bsum[blockIdx.x];
        for (int t = 0; t < 256; ++t) { int tmp = sm[t]; sm[t] = run; run += tmp; }
    }
    __syncthreads();
    int off = sm[threadIdx.x];
#pragma unroll
    for (int i = 0; i < SCAN_CH; ++i) {
        int idx = base + i;
        if (idx < TOT) { rp[idx] = off; off += pad8(deg[idx]); }
        else if (idx == TOT) rp[idx] = off;
    }
}

// bucketed scatter: only rows in [lo,hi) of this list; write window L2-sized
__global__ __launch_bounds__(256) void scatter_bucket_kernel(const int* __restrict__ rlist,
                                                             const int* __restrict__ clist,
                                                             int roff, int lo, int hi,
                                                             const int* __restrict__ rp,
                                                             int* __restrict__ cur,
                                                             int* __restrict__ ccol) {
    int e = blockIdx.x * 256 + threadIdx.x;
    if (e >= N_EDGES) return;
    int r0 = rlist[e];
    if (r0 < lo || r0 >= hi) return;
    int r = roff + r0;
    int pos = rp[r] + atomicAdd(&cur[r], 1);
    ccol[pos] = clist[e];
}

// ---------------- edge weights: pre-normalized+scaled; pad slots = {0,0} ----
__global__ __launch_bounds__(256) void edgeval_kernel(const int* __restrict__ rp,
                                                      const int* __restrict__ deg,
                                                      const int* __restrict__ ccol,
                                                      const float* __restrict__ f1,
                                                      const float* __restrict__ f2,
                                                      const float* __restrict__ pf1,
                                                      const float* __restrict__ pf2,
                                                      int2* __restrict__ eg) {
    int r = blockIdx.x * 16 + (threadIdx.x >> 4);
    int sl = threadIdx.x & 15;
    bool second = r >= N_NODES;
    float f1r = second ? pf1[r - N_NODES] : f1[r];
    const float* f2t = second ? pf2 : f2;
    float scale = second ? 0.8f : 0.2f;
    int j0 = rp[r];
    int realend = j0 + deg[r];
    int pend = rp[r + 1];
    float s = 0.f;
    for (int j = j0 + sl; j < realend; j += 16)
        s += __expf(f1r + f2t[ccol[j]]);
#pragma unroll
    for (int off = 8; off > 0; off >>= 1) s += __shfl_xor(s, off);
    float inv = s > 0.f ? scale / s : 0.f;
    for (int j = j0 + sl; j < pend; j += 16) {
        if (j < realend) {
            int c = ccol[j];
            float wv = __expf(f1r + f2t[c]) * inv;
            eg[j] = make_int2(c, __float_as_int(wv));
        } else {
            eg[j] = make_int2(0, 0);
        }
    }
}

// ---------------- fused SpMM on 128-wide bf16 H (encoder), unmasked ---------
#define SPU 8
__device__ inline void gat128(const int2* __restrict__ eg, int j,
                              const uint* __restrict__ Hu, int lane,
                              float& s0, float& s1) {
    int2 d[SPU];
#pragma unroll
    for (int u = 0; u < SPU; ++u) d[u] = eg[j + u];
    uint h[SPU];
#pragma unroll
    for (int u = 0; u < SPU; ++u) h[u] = Hu[(size_t)d[u].x * 64 + lane];
#pragma unroll
    for (int u = 0; u < SPU; ++u) {
        float v = __int_as_float(d[u].y);
        s0 += v * bf2f(h[u] & 0xffffu);
        s1 += v * bf2f(h[u] >> 16);
    }
}

__global__ __launch_bounds__(256) void spmm_fused_kernel(const int* __restrict__ rp,
                                                         const int2* __restrict__ eg,
                                                         const ushort* __restrict__ Hb,
                                                         float* __restrict__ out) {
    int r = blockIdx.x * 4 + (threadIdx.x >> 6);
    int lane = threadIdx.x & 63;
    const uint* Hu = reinterpret_cast<const uint*>(Hb);
    float a0 = 0.f, a1 = 0.f, b0 = 0.f, b1 = 0.f;
    int j1 = rp[r], E1 = rp[r + 1];
    int j2 = rp[N_NODES + r], E2 = rp[N_NODES + r + 1];
    while (j1 < E1 && j2 < E2) {
        int2 d1[SPU], d2[SPU];
#pragma unroll
        for (int u = 0; u < SPU; ++u) d1[u] = eg[j1 + u];
#pragma unroll
        for (int u = 0; u < SPU; ++u) d2[u] = eg[j2 + u];
        uint h1[SPU], h2[SPU];
#pragma unroll
        for (int u = 0; u < SPU; ++u) h1[u] = Hu[(size_t)d1[u].x * 64 + lane];
#pragma unroll
        for (int u = 0; u < SPU; ++u) h2[u] = Hu[(size_t)d2[u].x * 64 + lane];
#pragma unroll
        for (int u = 0; u < SPU; ++u) {
            float v1 = __int_as_float(d1[u].y);
            float v2 = __int_as_float(d2[u].y);
            a0 += v1 * bf2f(h1[u] & 0xffffu);
            a1 += v1 * bf2f(h1[u] >> 16);
            b0 += v2 * bf2f(h2[u] & 0xffffu);
            b1 += v2 * bf2f(h2[u] >> 16);
        }
        j1 += SPU; j2 += SPU;
    }
    while (j1 < E1) { gat128(eg, j1, Hu, lane, a0, a1); j1 += SPU; }
    while (j2 < E2) { gat128(eg, j2, Hu, lane, b0, b1); j2 += SPU; }
    float o0 = a0 + b0;
    float o1 = a1 + b1;
    o0 = o0 > 0.f ? o0 : expm1f(o0);
    o1 = o1 > 0.f ? o1 : expm1f(o1);
    *reinterpret_cast<float2*>(out + (size_t)r * 128 + 2 * lane) = make_float2(o0, o1);
}

// ---------------- fused SpMM on 64-wide bf16 Henc (decoder), unmasked -------
__device__ inline void gat64(const int2* __restrict__ eg, int j,
                             const ushort* __restrict__ Hb, int lane, float& s) {
    int2 d[SPU];
#pragma unroll
    for (int u = 0; u < SPU; ++u) d[u] = eg[j + u];
    ushort h[SPU];
#pragma unroll
    for (int u = 0; u < SPU; ++u) h[u] = Hb[(size_t)d[u].x * 64 + lane];
#pragma unroll
    for (int u = 0; u < SPU; ++u)
        s += __int_as_float(d[u].y) * bf2f((uint)h[u]);
}

__global__ __launch_bounds__(256) void spmm64_fused_kernel(const int* __restrict__ rp,
                                                           const int2* __restrict__ eg,
                                                           const ushort* __restrict__ Hb,
                                                           float* __restrict__ S) {
    int r = blockIdx.x * 4 + (threadIdx.x >> 6);
    int lane = threadIdx.x & 63;
    float a = 0.f, b = 0.f;
    int j1 = rp[r], E1 = rp[r + 1];
    int j2 = rp[N_NODES + r], E2 = rp[N_NODES + r + 1];
    while (j1 < E1 && j2 < E2) {
        int2 d1[SPU], d2[SPU];
#pragma unroll
        for (int u = 0; u < SPU; ++u) d1[u] = eg[j1 + u];
#pragma unroll
        for (int u = 0; u < SPU; ++u) d2[u] = eg[j2 + u];
        ushort h1[SPU], h2[SPU];
#pragma unroll
        for (int u = 0; u < SPU; ++u) h1[u] = Hb[(size_t)d1[u].x * 64 + lane];
#pragma unroll
        for (int u = 0; u < SPU; ++u) h2[u] = Hb[(size_t)d2[u].x * 64 + lane];
#pragma unroll
        for (int u = 0; u < SPU; ++u) {
            a += __int_as_float(d1[u].y) * bf2f((uint)h1[u]);
            b += __int_as_float(d2[u].y) * bf2f((uint)h2[u]);
        }
        j1 += SPU; j2 += SPU;
    }
    while (j1 < E1) { gat64(eg, j1, Hb, lane, a); j1 += SPU; }
    while (j2 < E2) { gat64(eg, j2, Hb, lane, b); j2 += SPU; }
    S[(size_t)r * 64 + lane] = a + b;
}

// ---------------- reductions -----------------------------------------------
__global__ __launch_bounds__(256) void sq_reduce_kernel(const float* __restrict__ a,
                                                        float* __restrict__ acc, int n) {
    __shared__ float sm[4];
    float s = 0.f;
    for (int i = blockIdx.x * 256 + threadIdx.x; i < n; i += gridDim.x * 256) {
        float d = a[i];
        s += d * d;
    }
#pragma unroll
    for (int off = 32; off > 0; off >>= 1) s += __shfl_down(s, off);
    int lane = threadIdx.x & 63, w = threadIdx.x >> 6;
    if (lane == 0) sm[w] = s;
    __syncthreads();
    if (threadIdx.x == 0) atomicAdd(acc, sm[0] + sm[1] + sm[2] + sm[3]);
}

__global__ __launch_bounds__(256) void partial_reduce_kernel(const float* __restrict__ p,
                                                             int n, float* __restrict__ acc) {
    __shared__ float sm[4];
    float s = 0.f;
    for (int i = threadIdx.x; i < n; i += 256) s += p[i];
#pragma unroll
    for (int off = 32; off > 0; off >>= 1) s += __shfl_down(s, off);
    int lane = threadIdx.x & 63, w = threadIdx.x >> 6;
    if (lane == 0) sm[w] = s;
    __syncthreads();
    if (threadIdx.x == 0) atomicAdd(acc, sm[0] + sm[1] + sm[2] + sm[3]);
}

__global__ void finalize_kernel(const float* __restrict__ acc, float* __restrict__ out) {
    out[0] = sqrtf(acc[0]) + 1e-4f * (acc[1] + acc[2]);
}

extern "C" void kernel_launch(void* const* d_in, const int* in_sizes, int n_in,
                              void* d_out, int out_size, void* d_ws, size_t ws_size,
                              hipStream_t stream) {
    const float* X    = (const float*)d_in[0];
    const float* W0   = (const float*)d_in[1];
    const float* W1   = (const float*)d_in[2];
    const float* v00  = (const float*)d_in[3];
    const float* v01  = (const float*)d_in[4];
    const float* pv00 = (const float*)d_in[5];
    const float* pv01 = (const float*)d_in[6];
    const int* rows   = (const int*)d_in[7];
    const int* cols   = (const int*)d_in[8];
    const int* prows  = (const int*)d_in[9];
    const int* pcols  = (const int*)d_in[10];

    float* out  = (float*)d_out;
    float* Henc = out + 1;                                  // N x 64 (misaligned base)
    float* Xrec = out + 1 + (size_t)N_NODES * 64;           // N x 256 (misaligned base)

    // scratch in dead X_ region [6400001, 32000001):
    //   bufAh/S [ 6400004, 12800004)  N x 128 bf16, later N x 64 fp32
    //   ccol    [12800004, 17600004)  4.8M int  (padded CSR capacity)
    //   eg      [17600004, 27200004)  4.8M int2
    //   HencB   [27200004, 28800004)  N x 64 bf16
    //   deg/cur [28800004, 29200004)  2N + 2N int
    ushort* bufAh  = (ushort*)(out + 6400004);
    float*  S      = out + 6400004;
    int*    ccol   = (int*)(out + 12800004);
    int2*   eg     = (int2*)(out + 17600004);
    ushort* HencB  = (ushort*)(out + 27200004);
    int*    deg    = (int*)(out + 28800004);
    int*    cur    = deg + TOT;

    float* ws   = (float*)d_ws;
    float* bufB = ws;                                       // N x 128 fp32 / bf16
    ushort* bufBh = (ushort*)bufB;
    float* f1   = bufB + (size_t)N_NODES * 128;
    float* f2   = f1 + N_NODES;
    float* pf1  = f2 + N_NODES;
    float* pf2  = pf1 + N_NODES;
    float* acc  = pf2 + N_NODES;                            // 4
    ushort* B1cm = (ushort*)(acc + 4);                      // 128 x 264
    ushort* B5cm = B1cm + 128 * 264;                        // 64 x 136
    ushort* B7cm = B5cm + 64 * 136;                         // 128 x 72
    ushort* B8cm = B7cm + 128 * 72;                         // 256 x 136
    int*   rp   = (int*)(B8cm + 256 * 136);                 // 2N+1
    int*   bsum = rp + TOT + 1;                             // SCAN_NB
    float* partial = (float*)(bsum + SCAN_NB);              // cdiv(n,128)

    const int n = N_NODES;
    const int EG = cdiv(N_EDGES, 256);
    const int EG2 = cdiv(2 * (long)N_EDGES, 256);

    // 0. weight prep (all bf16 col-major padded)
    prepB1_kernel<<<cdiv(256 * 128, 256), 256, 0, stream>>>(W0, B1cm);
    prepB5_kernel<<<cdiv(128 * 64, 256), 256, 0, stream>>>(W1, B5cm);
    prepB7_kernel<<<cdiv(128 * 64, 256), 256, 0, stream>>>(W1, B7cm);
    prepB8_kernel<<<cdiv(256 * 128, 256), 256, 0, stream>>>(W0, B8cm);

    // 1. H1 = X @ W0 -> bufAh (bf16), MFMA
    gemm_mfma<256, 128, true, 2, false, false><<<cdiv(n, 128), 256, 0, stream>>>(
        X, B1cm, bufAh, nullptr, nullptr, nullptr, n);

    // zero deg+cur (2*2N ints) and acc
    hipMemsetAsync(deg, 0, 2 * (size_t)TOT * sizeof(int), stream);
    hipMemsetAsync(acc, 0, 4 * sizeof(float), stream);

    // 2. attention feature dots
    attn_f4_kernel<<<cdiv(n, 4), 256, 0, stream>>>(bufAh, v00, v01, pv00, pv01,
                                                   f1, f2, pf1, pf2);

    // 3. padded CSR build (bucketed scatter) + pre-scaled softmax edge weights
    hist2_kernel<<<EG2, 256, 0, stream>>>(rows, prows, deg);
    scan1_kernel<<<SCAN_NB, 256, 0, stream>>>(deg, bsum);
    scan2_kernel<<<1, 64, 0, stream>>>(bsum);
    scan3_kernel<<<SCAN_NB, 256, 0, stream>>>(deg, bsum, rp);
    for (int p = 0; p < 4; ++p)
        scatter_bucket_kernel<<<EG, 256, 0, stream>>>(rows, cols, 0,
                                                      p * RPB, (p + 1) * RPB,
                                                      rp, cur, ccol);
    for (int p = 0; p < 4; ++p)
        scatter_bucket_kernel<<<EG, 256, 0, stream>>>(prows, pcols, N_NODES,
                                                      p * RPB, (p + 1) * RPB,
                                                      rp, cur, ccol);
    edgeval_kernel<<<cdiv(2 * n, 16), 256, 0, stream>>>(rp, deg, ccol,
                                                        f1, f2, pf1, pf2, eg);

    // 4. encoder: bufB(fp32) = elu(spmm)
    spmm_fused_kernel<<<n / 4, 256, 0, stream>>>(rp, eg, bufAh, bufB);

    // 5. Henc = bufB @ W1 -> d_out (fp32) + HencB (bf16), MFMA
    gemm_mfma<128, 64, true, 3, false, false><<<cdiv(n, 128), 256, 0, stream>>>(
        bufB, B5cm, Henc, HencB, nullptr, nullptr, n);

    // 6. decoder spmm on Henc (64-wide) -> S (bufAh region, now dead)
    spmm64_fused_kernel<<<n / 4, 256, 0, stream>>>(rp, eg, HencB, S);

    // 7. D = elu(S @ W1T) -> bufBh (bf16), MFMA
    gemm_mfma<64, 128, true, 2, true, false><<<cdiv(n, 128), 256, 0, stream>>>(
        S, B7cm, bufBh, nullptr, nullptr, nullptr, n);

    // 8. X_ = bufBh @ W0T -> Xrec + fused loss partials, MFMA
    gemm_mfma<128, 256, false, 0, false, true><<<cdiv(n, 128), 256, 0, stream>>>(
        bufBh, B8cm, Xrec, nullptr, X, partial, n);

    // 9. loss
    partial_reduce_kernel<<<1, 256, 0, stream>>>(partial, cdiv(n, 128), acc + 0);
    sq_reduce_kernel<<<16, 256, 0, stream>>>(W0, acc + 1, 256 * 128);
    sq_reduce_kernel<<<4, 256, 0, stream>>>(W1, acc + 2, 128 * 64);
    finalize_kernel<<<1, 1, 0, stream>>>(acc, out);
}

// Round 14
// 799.666 us; speedup vs baseline: 1.3105x; 1.0294x over previous
//
#include <hip/hip_runtime.h>
#include <math.h>

#define N_NODES 100000
#define N_EDGES 1600000
#define TOT (2 * N_NODES)            // CSR buckets: 2*row + adj
#define SCAN_NB 256
#define SCAN_CH 4                    // 256*256*4 = 262144 >= 2N+1
#define RPB 25000                    // rows per scatter bucket pass

static inline int cdiv(long a, long b) { return (int)((a + b - 1) / b); }

typedef unsigned int uint;
typedef unsigned short ushort;
typedef __attribute__((ext_vector_type(8))) short short8v;   // 8 bf16 (4 VGPR)
typedef __attribute__((ext_vector_type(4))) float f32x4;

__device__ inline float bf2f(uint u) { return __uint_as_float(u << 16); }
__device__ inline ushort f2bf(float f) {
    uint u = __float_as_uint(f);
    uint r = ((u >> 16) & 1u) + 0x7fffu;   // RNE
    return (ushort)((u + r) >> 16);
}

// ---------------- MFMA bf16 GEMM: C[i,m] = sum_k A[i,k]*B[k,m] --------------
template <int K, int M, bool AF32, int OUT, bool ELU, bool LOSS>
__global__ __launch_bounds__(256) void gemm_mfma(const void* __restrict__ Av,
                                                 const ushort* __restrict__ Bcm,
                                                 void* __restrict__ Cv,
                                                 void* __restrict__ Cv2,
                                                 const float* __restrict__ Xref,
                                                 float* __restrict__ partial,
                                                 int nrows) {
    constexpr int BM = 128;
    constexpr int KP = K + 8;
    constexpr int NCT = M / 16;
    __shared__ ushort Blds[M * KP];
    __shared__ ushort Alds[BM * 32];
    const int w = threadIdx.x >> 6;
    const int l = threadIdx.x & 63;
    const int rowg = l & 15;
    const int kg = l >> 4;
    const int rbase = blockIdx.x * BM;
    {
        const uint4* src = reinterpret_cast<const uint4*>(Bcm);
        uint4* dst = reinterpret_cast<uint4*>(Blds);
        const int total = M * KP / 8;
        for (int i = threadIdx.x; i < total; i += 256) dst[i] = src[i];
    }
    f32x4 acc[2][NCT] = {};
    for (int k0 = 0; k0 < K; k0 += 32) {
        __syncthreads();
        int r = threadIdx.x >> 1;
        int kk = (threadIdx.x & 1) * 16;
        int rg = min(rbase + r, nrows - 1);
        if (AF32) {
            const float* A = (const float*)Av;
            const float4* src = reinterpret_cast<const float4*>(A + (size_t)rg * K + k0 + kk);
            ushort* dst = &Alds[r * 32 + kk];
#pragma unroll
            for (int q = 0; q < 4; ++q) {
                float4 v = src[q];
                dst[4 * q + 0] = f2bf(v.x); dst[4 * q + 1] = f2bf(v.y);
                dst[4 * q + 2] = f2bf(v.z); dst[4 * q + 3] = f2bf(v.w);
            }
        } else {
            const ushort* A = (const ushort*)Av;
            const uint4* src = reinterpret_cast<const uint4*>(A + (size_t)rg * K + k0 + kk);
            uint4* dst = reinterpret_cast<uint4*>(&Alds[r * 32 + kk]);
            dst[0] = src[0];
            dst[1] = src[1];
        }
        __syncthreads();
#pragma unroll
        for (int rt = 0; rt < 2; ++rt) {
            short8v af = *reinterpret_cast<const short8v*>(
                &Alds[(w * 32 + rt * 16 + rowg) * 32 + kg * 8]);
#pragma unroll
            for (int ct = 0; ct < NCT; ++ct) {
                short8v bf = *reinterpret_cast<const short8v*>(
                    &Blds[(ct * 16 + rowg) * KP + k0 + kg * 8]);
                acc[rt][ct] = __builtin_amdgcn_mfma_f32_16x16x32_bf16(
                    af, bf, acc[rt][ct], 0, 0, 0);
            }
        }
    }
    float lsum = 0.f;
#pragma unroll
    for (int rt = 0; rt < 2; ++rt) {
#pragma unroll
        for (int q = 0; q < 4; ++q) {
            int r = rbase + w * 32 + rt * 16 + kg * 4 + q;
            if (r >= nrows) continue;
#pragma unroll
            for (int ct = 0; ct < NCT; ++ct) {
                float o = acc[rt][ct][q];
                if (ELU) o = o > 0.f ? o : expm1f(o);
                int col = ct * 16 + rowg;
                if (OUT == 0 || OUT == 3) ((float*)Cv)[(size_t)r * M + col] = o;
                if (OUT == 2) ((ushort*)Cv)[(size_t)r * M + col] = f2bf(o);
                if (OUT == 3) ((ushort*)Cv2)[(size_t)r * M + col] = f2bf(o);
                if (LOSS) {
                    float d = o - Xref[(size_t)r * 256 + col];
                    lsum += d * d;
                }
            }
        }
    }
    if (LOSS) {
        __shared__ float smRed[4];
#pragma unroll
        for (int off = 32; off > 0; off >>= 1) lsum += __shfl_down(lsum, off);
        __syncthreads();
        if (l == 0) smRed[w] = lsum;
        __syncthreads();
        if (threadIdx.x == 0)
            partial[blockIdx.x] = smRed[0] + smRed[1] + smRed[2] + smRed[3];
    }
}

// ---------------- weight prep (bf16 col-major padded) -----------------------
__global__ __launch_bounds__(256) void prepB1_kernel(const float* __restrict__ W0,
                                                     ushort* __restrict__ B) {
    int i = blockIdx.x * 256 + threadIdx.x;
    if (i >= 256 * 128) return;
    int k = i / 128, m = i - k * 128;
    B[m * 264 + k] = f2bf(W0[i]);
}
__global__ __launch_bounds__(256) void prepB5_kernel(const float* __restrict__ W1,
                                                     ushort* __restrict__ B) {
    int i = blockIdx.x * 256 + threadIdx.x;
    if (i >= 128 * 64) return;
    int k = i / 64, m = i - k * 64;
    B[m * 136 + k] = f2bf(W1[i]);
}
__global__ __launch_bounds__(256) void prepB7_kernel(const float* __restrict__ W1,
                                                     ushort* __restrict__ B) {
    int i = blockIdx.x * 256 + threadIdx.x;
    if (i >= 128 * 64) return;
    int m = i / 64, k = i - m * 64;
    B[m * 72 + k] = f2bf(W1[i]);
}
__global__ __launch_bounds__(256) void prepB8_kernel(const float* __restrict__ W0,
                                                     ushort* __restrict__ B) {
    int i = blockIdx.x * 256 + threadIdx.x;
    if (i >= 256 * 128) return;
    int m = i / 128, k = i - m * 128;
    B[m * 136 + k] = f2bf(W0[i]);
}

// ---------------- attention feature dots (bf16 H): all 4 at once ------------
__global__ __launch_bounds__(256) void attn_f4_kernel(const ushort* __restrict__ Hb,
                                                      const float* __restrict__ va,
                                                      const float* __restrict__ vb,
                                                      const float* __restrict__ pva,
                                                      const float* __restrict__ pvb,
                                                      float* __restrict__ f1,
                                                      float* __restrict__ f2,
                                                      float* __restrict__ pf1,
                                                      float* __restrict__ pf2) {
    int wid = (blockIdx.x * 256 + threadIdx.x) >> 6;
    int lane = threadIdx.x & 63;
    if (wid >= N_NODES) return;
    uint hv = reinterpret_cast<const uint*>(Hb + (size_t)wid * 128)[lane];
    float x0 = bf2f(hv & 0xffffu);
    float x1 = bf2f(hv >> 16);
    int k = 2 * lane;
    float a = x0 * va[k] + x1 * va[k + 1];
    float b = x0 * vb[k] + x1 * vb[k + 1];
    float pa = x0 * pva[k] + x1 * pva[k + 1];
    float pb = x0 * pvb[k] + x1 * pvb[k + 1];
#pragma unroll
    for (int off = 32; off > 0; off >>= 1) {
        a += __shfl_down(a, off);
        b += __shfl_down(b, off);
        pa += __shfl_down(pa, off);
        pb += __shfl_down(pb, off);
    }
    if (lane == 0) { f1[wid] = a; f2[wid] = b; pf1[wid] = pa; pf2[wid] = pb; }
}

// ---------------- CSR build: bucket = 2*row + adj, rows padded to x8 --------
__global__ __launch_bounds__(256) void hist2_kernel(const int* __restrict__ rows,
                                                    const int* __restrict__ prows,
                                                    int* __restrict__ deg) {
    int e = blockIdx.x * 256 + threadIdx.x;
    if (e >= 2 * N_EDGES) return;
    int b = e < N_EDGES ? rows[e] * 2 : prows[e - N_EDGES] * 2 + 1;
    atomicAdd(&deg[b], 1);
}

__device__ inline int pad8(int d) { return (d + 7) & ~7; }

__global__ __launch_bounds__(256) void scan1_kernel(const int* __restrict__ deg,
                                                    int* __restrict__ bsum) {
    __shared__ int sm[256];
    int base = (blockIdx.x * 256 + threadIdx.x) * SCAN_CH;
    int s = 0;
#pragma unroll
    for (int i = 0; i < SCAN_CH; ++i) {
        int idx = base + i;
        if (idx < TOT) s += pad8(deg[idx]);
    }
    sm[threadIdx.x] = s;
    __syncthreads();
    for (int off = 128; off > 0; off >>= 1) {
        if (threadIdx.x < off) sm[threadIdx.x] += sm[threadIdx.x + off];
        __syncthreads();
    }
    if (threadIdx.x == 0) bsum[blockIdx.x] = sm[0];
}

__global__ void scan2_kernel(int* __restrict__ bsum) {
    if (threadIdx.x != 0) return;
    int run = 0;
    for (int i = 0; i < SCAN_NB; ++i) {
        int t = bsum[i];
        bsum[i] = run;
        run += t;
    }
}

__global__ __launch_bounds__(256) void scan3_kernel(const int* __restrict__ deg,
                                                    const int* __restrict__ bsum,
                                                    int* __restrict__ rp) {
    __shared__ int sm[256];
    int base = (blockIdx.x * 256 + threadIdx.x) * SCAN_CH;
    int s = 0;
#pragma unroll
    for (int i = 0; i < SCAN_CH; ++i) {
        int idx = base + i;
        if (idx < TOT) s += pad8(deg[idx]);
    }
    sm[threadIdx.x] = s;
    __syncthreads();
    if (threadIdx.x == 0) {
        int run = bsum[blockIdx.x];
        for (int t = 0; t < 256; ++t) { int tmp = sm[t]; sm[t] = run; run += tmp; }
    }
    __syncthreads();
    int off = sm[threadIdx.x];
#pragma unroll
    for (int i = 0; i < SCAN_CH; ++i) {
        int idx = base + i;
        if (idx < TOT) { rp[idx] = off; off += pad8(deg[idx]); }
        else if (idx == TOT) rp[idx] = off;
    }
}

// bucketed scatter: only rows in [lo,hi) of one list; adj selects bucket parity
__global__ __launch_bounds__(256) void scatter_bucket_kernel(const int* __restrict__ rlist,
                                                             const int* __restrict__ clist,
                                                             int adj, int lo, int hi,
                                                             const int* __restrict__ rp,
                                                             int* __restrict__ cur,
                                                             int* __restrict__ ccol) {
    int e = blockIdx.x * 256 + threadIdx.x;
    if (e >= N_EDGES) return;
    int r0 = rlist[e];
    if (r0 < lo || r0 >= hi) return;
    int b = r0 * 2 + adj;
    int pos = rp[b] + atomicAdd(&cur[b], 1);
    ccol[pos] = clist[e];
}

// ---------------- edge weights per bucket; pad slots = {0, 0.0f} ------------
__global__ __launch_bounds__(256) void edgeval_kernel(const int* __restrict__ rp,
                                                      const int* __restrict__ deg,
                                                      const int* __restrict__ ccol,
                                                      const float* __restrict__ f1,
                                                      const float* __restrict__ f2,
                                                      const float* __restrict__ pf1,
                                                      const float* __restrict__ pf2,
                                                      int2* __restrict__ eg) {
    int b = blockIdx.x * 16 + (threadIdx.x >> 4);
    int sl = threadIdx.x & 15;
    int adj = b & 1, r = b >> 1;
    float f1r = adj ? pf1[r] : f1[r];
    const float* f2t = adj ? pf2 : f2;
    float scale = adj ? 0.8f : 0.2f;
    int j0 = rp[b];
    int realend = j0 + deg[b];
    int pend = rp[b + 1];
    float s = 0.f;
    for (int j = j0 + sl; j < realend; j += 16)
        s += __expf(f1r + f2t[ccol[j]]);
#pragma unroll
    for (int off = 8; off > 0; off >>= 1) s += __shfl_xor(s, off);
    float inv = s > 0.f ? scale / s : 0.f;
    for (int j = j0 + sl; j < pend; j += 16) {
        if (j < realend) {
            int c = ccol[j];
            float wv = __expf(f1r + f2t[c]) * inv;
            eg[j] = make_int2(c, __float_as_int(wv));
        } else {
            eg[j] = make_int2(0, 0);
        }
    }
}

// ---------------- fused SpMM, unified row stream, 2-stage pipeline ----------
#define SPU 8
__global__ __launch_bounds__(256) void spmm_fused_kernel(const int* __restrict__ rp,
                                                         const int2* __restrict__ eg,
                                                         const ushort* __restrict__ Hb,
                                                         float* __restrict__ out) {
    int r = blockIdx.x * 4 + (threadIdx.x >> 6);
    int lane = threadIdx.x & 63;
    const uint* Hu = reinterpret_cast<const uint*>(Hb);
    float a0 = 0.f, a1 = 0.f;
    int j = rp[2 * r], E = rp[2 * r + 2];
    if (j < E) {
        int2 d[SPU]; uint h[SPU];
#pragma unroll
        for (int u = 0; u < SPU; ++u) d[u] = eg[j + u];
#pragma unroll
        for (int u = 0; u < SPU; ++u) h[u] = Hu[(uint)d[u].x * 64u + lane];
        j += SPU;
        for (; j < E; j += SPU) {
            int2 dn[SPU]; uint hn[SPU];
#pragma unroll
            for (int u = 0; u < SPU; ++u) dn[u] = eg[j + u];
#pragma unroll
            for (int u = 0; u < SPU; ++u) hn[u] = Hu[(uint)dn[u].x * 64u + lane];
#pragma unroll
            for (int u = 0; u < SPU; ++u) {
                float v = __int_as_float(d[u].y);
                a0 += v * bf2f(h[u] & 0xffffu);
                a1 += v * bf2f(h[u] >> 16);
            }
#pragma unroll
            for (int u = 0; u < SPU; ++u) { d[u] = dn[u]; h[u] = hn[u]; }
        }
#pragma unroll
        for (int u = 0; u < SPU; ++u) {
            float v = __int_as_float(d[u].y);
            a0 += v * bf2f(h[u] & 0xffffu);
            a1 += v * bf2f(h[u] >> 16);
        }
    }
    float o0 = a0 > 0.f ? a0 : expm1f(a0);
    float o1 = a1 > 0.f ? a1 : expm1f(a1);
    *reinterpret_cast<float2*>(out + (size_t)r * 128 + 2 * lane) = make_float2(o0, o1);
}

__global__ __launch_bounds__(256) void spmm64_fused_kernel(const int* __restrict__ rp,
                                                           const int2* __restrict__ eg,
                                                           const ushort* __restrict__ Hb,
                                                           float* __restrict__ S) {
    int r = blockIdx.x * 4 + (threadIdx.x >> 6);
    int lane = threadIdx.x & 63;
    float a = 0.f;
    int j = rp[2 * r], E = rp[2 * r + 2];
    if (j < E) {
        int2 d[SPU]; ushort h[SPU];
#pragma unroll
        for (int u = 0; u < SPU; ++u) d[u] = eg[j + u];
#pragma unroll
        for (int u = 0; u < SPU; ++u) h[u] = Hb[(uint)d[u].x * 64u + lane];
        j += SPU;
        for (; j < E; j += SPU) {
            int2 dn[SPU]; ushort hn[SPU];
#pragma unroll
            for (int u = 0; u < SPU; ++u) dn[u] = eg[j + u];
#pragma unroll
            for (int u = 0; u < SPU; ++u) hn[u] = Hb[(uint)dn[u].x * 64u + lane];
#pragma unroll
            for (int u = 0; u < SPU; ++u)
                a += __int_as_float(d[u].y) * bf2f((uint)h[u]);
#pragma unroll
            for (int u = 0; u < SPU; ++u) { d[u] = dn[u]; h[u] = hn[u]; }
        }
#pragma unroll
        for (int u = 0; u < SPU; ++u)
            a += __int_as_float(d[u].y) * bf2f((uint)h[u]);
    }
    S[(size_t)r * 64 + lane] = a;
}

// ---------------- reductions -----------------------------------------------
__global__ __launch_bounds__(256) void sq_reduce_kernel(const float* __restrict__ a,
                                                        float* __restrict__ acc, int n) {
    __shared__ float sm[4];
    float s = 0.f;
    for (int i = blockIdx.x * 256 + threadIdx.x; i < n; i += gridDim.x * 256) {
        float d = a[i];
        s += d * d;
    }
#pragma unroll
    for (int off = 32; off > 0; off >>= 1) s += __shfl_down(s, off);
    int lane = threadIdx.x & 63, w = threadIdx.x >> 6;
    if (lane == 0) sm[w] = s;
    __syncthreads();
    if (threadIdx.x == 0) atomicAdd(acc, sm[0] + sm[1] + sm[2] + sm[3]);
}

__global__ __launch_bounds__(256) void partial_reduce_kernel(const float* __restrict__ p,
                                                             int n, float* __restrict__ acc) {
    __shared__ float sm[4];
    float s = 0.f;
    for (int i = threadIdx.x; i < n; i += 256) s += p[i];
#pragma unroll
    for (int off = 32; off > 0; off >>= 1) s += __shfl_down(s, off);
    int lane = threadIdx.x & 63, w = threadIdx.x >> 6;
    if (lane == 0) sm[w] = s;
    __syncthreads();
    if (threadIdx.x == 0) atomicAdd(acc, sm[0] + sm[1] + sm[2] + sm[3]);
}

__global__ void finalize_kernel(const float* __restrict__ acc, float* __restrict__ out) {
    out[0] = sqrtf(acc[0]) + 1e-4f * (acc[1] + acc[2]);
}

extern "C" void kernel_launch(void* const* d_in, const int* in_sizes, int n_in,
                              void* d_out, int out_size, void* d_ws, size_t ws_size,
                              hipStream_t stream) {
    const float* X    = (const float*)d_in[0];
    const float* W0   = (const float*)d_in[1];
    const float* W1   = (const float*)d_in[2];
    const float* v00  = (const float*)d_in[3];
    const float* v01  = (const float*)d_in[4];
    const float* pv00 = (const float*)d_in[5];
    const float* pv01 = (const float*)d_in[6];
    const int* rows   = (const int*)d_in[7];
    const int* cols   = (const int*)d_in[8];
    const int* prows  = (const int*)d_in[9];
    const int* pcols  = (const int*)d_in[10];

    float* out  = (float*)d_out;
    float* Henc = out + 1;                                  // N x 64 (misaligned base)
    float* Xrec = out + 1 + (size_t)N_NODES * 64;           // N x 256 (misaligned base)

    // scratch in dead X_ region [6400001, 32000001):
    ushort* bufAh  = (ushort*)(out + 6400004);              // N x 128 bf16
    float*  S      = out + 6400004;                         // N x 64 fp32 (after bufAh dead)
    int*    ccol   = (int*)(out + 12800004);                // 4.8M int (padded CSR)
    int2*   eg     = (int2*)(out + 17600004);               // 4.8M int2
    ushort* HencB  = (ushort*)(out + 27200004);             // N x 64 bf16
    int*    deg    = (int*)(out + 28800004);                // 2N
    int*    cur    = deg + TOT;                             // 2N

    float* ws   = (float*)d_ws;
    float* bufB = ws;                                       // N x 128 fp32 / bf16
    ushort* bufBh = (ushort*)bufB;
    float* f1   = bufB + (size_t)N_NODES * 128;
    float* f2   = f1 + N_NODES;
    float* pf1  = f2 + N_NODES;
    float* pf2  = pf1 + N_NODES;
    float* acc  = pf2 + N_NODES;                            // 4
    ushort* B1cm = (ushort*)(acc + 4);                      // 128 x 264
    ushort* B5cm = B1cm + 128 * 264;                        // 64 x 136
    ushort* B7cm = B5cm + 64 * 136;                         // 128 x 72
    ushort* B8cm = B7cm + 128 * 72;                         // 256 x 136
    int*   rp   = (int*)(B8cm + 256 * 136);                 // 2N+1
    int*   bsum = rp + TOT + 1;                             // SCAN_NB
    float* partial = (float*)(bsum + SCAN_NB);              // cdiv(n,128)

    const int n = N_NODES;
    const int EG = cdiv(N_EDGES, 256);
    const int EG2 = cdiv(2 * (long)N_EDGES, 256);

    // 0. weight prep (all bf16 col-major padded)
    prepB1_kernel<<<cdiv(256 * 128, 256), 256, 0, stream>>>(W0, B1cm);
    prepB5_kernel<<<cdiv(128 * 64, 256), 256, 0, stream>>>(W1, B5cm);
    prepB7_kernel<<<cdiv(128 * 64, 256), 256, 0, stream>>>(W1, B7cm);
    prepB8_kernel<<<cdiv(256 * 128, 256), 256, 0, stream>>>(W0, B8cm);

    // 1. H1 = X @ W0 -> bufAh (bf16), MFMA
    gemm_mfma<256, 128, true, 2, false, false><<<cdiv(n, 128), 256, 0, stream>>>(
        X, B1cm, bufAh, nullptr, nullptr, nullptr, n);

    // zero deg+cur and acc
    hipMemsetAsync(deg, 0, 2 * (size_t)TOT * sizeof(int), stream);
    hipMemsetAsync(acc, 0, 4 * sizeof(float), stream);

    // 2. attention feature dots
    attn_f4_kernel<<<cdiv(n, 4), 256, 0, stream>>>(bufAh, v00, v01, pv00, pv01,
                                                   f1, f2, pf1, pf2);

    // 3. padded interleaved CSR (bucket = 2r+adj) + pre-scaled softmax weights
    hist2_kernel<<<EG2, 256, 0, stream>>>(rows, prows, deg);
    scan1_kernel<<<SCAN_NB, 256, 0, stream>>>(deg, bsum);
    scan2_kernel<<<1, 64, 0, stream>>>(bsum);
    scan3_kernel<<<SCAN_NB, 256, 0, stream>>>(deg, bsum, rp);
    for (int p = 0; p < 4; ++p)
        scatter_bucket_kernel<<<EG, 256, 0, stream>>>(rows, cols, 0,
                                                      p * RPB, (p + 1) * RPB,
                                                      rp, cur, ccol);
    for (int p = 0; p < 4; ++p)
        scatter_bucket_kernel<<<EG, 256, 0, stream>>>(prows, pcols, 1,
                                                      p * RPB, (p + 1) * RPB,
                                                      rp, cur, ccol);
    edgeval_kernel<<<cdiv(TOT, 16), 256, 0, stream>>>(rp, deg, ccol,
                                                      f1, f2, pf1, pf2, eg);

    // 4. encoder: bufB(fp32) = elu(spmm)
    spmm_fused_kernel<<<n / 4, 256, 0, stream>>>(rp, eg, bufAh, bufB);

    // 5. Henc = bufB @ W1 -> d_out (fp32) + HencB (bf16), MFMA
    gemm_mfma<128, 64, true, 3, false, false><<<cdiv(n, 128), 256, 0, stream>>>(
        bufB, B5cm, Henc, HencB, nullptr, nullptr, n);

    // 6. decoder spmm on Henc (64-wide) -> S (bufAh region, now dead)
    spmm64_fused_kernel<<<n / 4, 256, 0, stream>>>(rp, eg, HencB, S);

    // 7. D = elu(S @ W1T) -> bufBh (bf16), MFMA
    gemm_mfma<64, 128, true, 2, true, false><<<cdiv(n, 128), 256, 0, stream>>>(
        S, B7cm, bufBh, nullptr, nullptr, nullptr, n);

    // 8. X_ = bufBh @ W0T -> Xrec + fused loss partials, MFMA
    gemm_mfma<128, 256, false, 0, false, true><<<cdiv(n, 128), 256, 0, stream>>>(
        bufBh, B8cm, Xrec, nullptr, X, partial, n);

    // 9. loss
    partial_reduce_kernel<<<1, 256, 0, stream>>>(partial, cdiv(n, 128), acc + 0);
    sq_reduce_kernel<<<16, 256, 0, stream>>>(W0, acc + 1, 256 * 128);
    sq_reduce_kernel<<<4, 256, 0, stream>>>(W1, acc + 2, 128 * 64);
    finalize_kernel<<<1, 1, 0, stream>>>(acc, out);
}